// Round 6
// baseline (1279.097 us; speedup 1.0000x reference)
//
#include <hip/hip_runtime.h>

#define SEQ 2048
#define NVAR 64
#define DMODEL 512
#define BSZ 128
#define KC 64
#define NPT (BSZ*NVAR)   /* 8192 points */
#define MAXIT 10

typedef __bf16 bf16x8 __attribute__((ext_vector_type(8)));
typedef float f32x4 __attribute__((ext_vector_type(4)));

__device__ __forceinline__ void load_lds16(const void* g, void* l) {
  __builtin_amdgcn_global_load_lds((const __attribute__((address_space(1))) void*)g,
                                   (__attribute__((address_space(3))) void*)l, 16, 0, 0);
}

__device__ __forceinline__ unsigned short bf16_rn(float x) {
  unsigned int u = __float_as_uint(x);
  u += 0x7fffu + ((u >> 16) & 1u);
  return (unsigned short)(u >> 16);
}

// ---------------------------------------------------------------------------
// init: cent/centh/centl from c0, per-quarter csq4[dq][k], zero flags + bar.
// grid 64, block 256.
// ---------------------------------------------------------------------------
__global__ __launch_bounds__(256) void init_k(const float* __restrict__ c0,
    float* __restrict__ cent, unsigned short* __restrict__ centh,
    unsigned short* __restrict__ centl, float* __restrict__ csq4,
    int* __restrict__ done, float* __restrict__ shift2, int* __restrict__ ticket,
    int* __restrict__ bar) {
  const int k = blockIdx.x, t = threadIdx.x;
  __shared__ float red[256];
  float v0, v1;
  {
    int d = t;                       // 0..255 (quarters 0,1)
    v0 = c0[k * DMODEL + d];
    cent[k * DMODEL + d] = v0;
    unsigned short h = bf16_rn(v0);
    centh[k * DMODEL + d] = h;
    centl[k * DMODEL + d] = bf16_rn(v0 - __uint_as_float((unsigned)h << 16));
  }
  {
    int d = t + 256;                 // 256..511 (quarters 2,3)
    v1 = c0[k * DMODEL + d];
    cent[k * DMODEL + d] = v1;
    unsigned short h = bf16_rn(v1);
    centh[k * DMODEL + d] = h;
    centl[k * DMODEL + d] = bf16_rn(v1 - __uint_as_float((unsigned)h << 16));
  }
  // per-128-d-quarter sum of squares
  red[t] = v0 * v0; __syncthreads();
  for (int s = 64; s > 0; s >>= 1) { if ((t & 127) < s) red[t] += red[t + s]; __syncthreads(); }
  if (t == 0)   csq4[0 * KC + k] = red[0];
  if (t == 128) csq4[1 * KC + k] = red[128];
  __syncthreads();
  red[t] = v1 * v1; __syncthreads();
  for (int s = 64; s > 0; s >>= 1) { if ((t & 127) < s) red[t] += red[t + s]; __syncthreads(); }
  if (t == 0)   csq4[2 * KC + k] = red[0];
  if (t == 128) csq4[3 * KC + k] = red[128];
  if (k == 0 && t < MAXIT) { shift2[t] = 0.f; ticket[t] = 0; }
  if (k == 0) { bar[t] = 0; if (t < 64) bar[256 + t] = 0; }
  if (k == 0 && t == 31) *done = 0;
}

// ---------------------------------------------------------------------------
// conv_w: W fp32 -> hi/lo bf16.  grid 1024 x 256.
// ---------------------------------------------------------------------------
__global__ __launch_bounds__(256) void conv_w(const float* __restrict__ W,
    unsigned short* __restrict__ Wh, unsigned short* __restrict__ Wl) {
  int i = (blockIdx.x * 256 + threadIdx.x) * 4;
  float4 v = *(const float4*)(W + i);
  ushort4 h, l;
  h.x = bf16_rn(v.x); l.x = bf16_rn(v.x - __uint_as_float((unsigned)h.x << 16));
  h.y = bf16_rn(v.y); l.y = bf16_rn(v.y - __uint_as_float((unsigned)h.y << 16));
  h.z = bf16_rn(v.z); l.z = bf16_rn(v.z - __uint_as_float((unsigned)h.z << 16));
  h.w = bf16_rn(v.w); l.w = bf16_rn(v.w - __uint_as_float((unsigned)h.w << 16));
  *(ushort4*)(Wh + i) = h;
  *(ushort4*)(Wl + i) = l;
}

// ---------------------------------------------------------------------------
// conv_x: x[bs][k][v] -> xt hi/lo [bs*64+v][k].  grid (32,128) x 256.
// ---------------------------------------------------------------------------
__global__ __launch_bounds__(256) void conv_x(const float* __restrict__ x,
    unsigned short* __restrict__ Xh, unsigned short* __restrict__ Xl) {
  __shared__ float tile[64 * 65];
  const int k0 = blockIdx.x * 64;
  const int bs = blockIdx.y;
  const int t = threadIdx.x;
  const float* xb = x + (size_t)bs * SEQ * NVAR + (size_t)k0 * NVAR;
  #pragma unroll
  for (int p = 0; p < 4; ++p) {
    int idx = t + 256 * p;
    int row = idx >> 4, c4 = (idx & 15) * 4;
    float4 v = *(const float4*)(xb + row * NVAR + c4);
    tile[row * 65 + c4 + 0] = v.x; tile[row * 65 + c4 + 1] = v.y;
    tile[row * 65 + c4 + 2] = v.z; tile[row * 65 + c4 + 3] = v.w;
  }
  __syncthreads();
  const int v = t >> 2;
  const int kc = (t & 3) * 16;
  unsigned short h[16], l[16];
  #pragma unroll
  for (int j = 0; j < 16; ++j) {
    float f = tile[(kc + j) * 65 + v];
    h[j] = bf16_rn(f);
    l[j] = bf16_rn(f - __uint_as_float((unsigned)h[j] << 16));
  }
  size_t off = (size_t)(bs * 64 + v) * SEQ + k0 + kc;
  *(uint4*)(Xh + off)     = *(uint4*)&h[0];
  *(uint4*)(Xh + off + 8) = *(uint4*)&h[8];
  *(uint4*)(Xl + off)     = *(uint4*)&l[0];
  *(uint4*)(Xl + off + 8) = *(uint4*)&l[8];
}

// ---------------------------------------------------------------------------
// gemm_mfma: emb = Xt·W^T + b, bf16x3 split.  Tile 32m x 256n, BK=64.
// grid (256 m, 2 n).
// ---------------------------------------------------------------------------
__global__ __launch_bounds__(256) void gemm_mfma(
    const unsigned short* __restrict__ Ah, const unsigned short* __restrict__ Al,
    const unsigned short* __restrict__ Bh, const unsigned short* __restrict__ Bl,
    const float* __restrict__ bias, float* __restrict__ emb) {
  __shared__ unsigned short sAh[32 * 64] __attribute__((aligned(16)));
  __shared__ unsigned short sAl[32 * 64] __attribute__((aligned(16)));
  __shared__ unsigned short sBh[256 * 64] __attribute__((aligned(16)));
  __shared__ unsigned short sBl[256 * 64] __attribute__((aligned(16)));
  const int t = threadIdx.x;
  const int w = t >> 6, lane = t & 63;
  const int m0 = blockIdx.x * 32;
  const int n0 = blockIdx.y * 256;
  const int wn = w * 64;
  const int lrow = lane >> 3, sl8 = lane & 7;
  const int csrc = sl8 ^ lrow;

  f32x4 acc[2][4];
  #pragma unroll
  for (int i = 0; i < 2; ++i)
    #pragma unroll
    for (int j = 0; j < 4; ++j) acc[i][j] = (f32x4){0.f, 0.f, 0.f, 0.f};

  for (int kt = 0; kt < SEQ; kt += 64) {
    __syncthreads();
    {
      const int r = w * 8 + lrow;          // A rows 0..31
      const size_t ga = (size_t)(m0 + r) * SEQ + kt + csrc * 8;
      load_lds16(Ah + ga, &sAh[r * 64 + sl8 * 8]);
      load_lds16(Al + ga, &sAl[r * 64 + sl8 * 8]);
    }
    #pragma unroll
    for (int i = 0; i < 8; ++i) {
      const int r = w * 64 + i * 8 + lrow; // B rows 0..255
      const size_t gb = (size_t)(n0 + r) * SEQ + kt + csrc * 8;
      load_lds16(Bh + gb, &sBh[r * 64 + sl8 * 8]);
      load_lds16(Bl + gb, &sBl[r * 64 + sl8 * 8]);
    }
    __syncthreads();
    #pragma unroll
    for (int kk = 0; kk < 2; ++kk) {
      const int sl = ((kk * 4 + (lane >> 4)) ^ (lane & 7)) * 8;
      bf16x8 ah[2], al[2], bh[4], bl[4];
      #pragma unroll
      for (int mi = 0; mi < 2; ++mi) {
        int off = (mi * 16 + (lane & 15)) * 64 + sl;
        ah[mi] = *(const bf16x8*)&sAh[off];
        al[mi] = *(const bf16x8*)&sAl[off];
      }
      #pragma unroll
      for (int ni = 0; ni < 4; ++ni) {
        int off = (wn + ni * 16 + (lane & 15)) * 64 + sl;
        bh[ni] = *(const bf16x8*)&sBh[off];
        bl[ni] = *(const bf16x8*)&sBl[off];
      }
      #pragma unroll
      for (int mi = 0; mi < 2; ++mi)
        #pragma unroll
        for (int ni = 0; ni < 4; ++ni) {
          acc[mi][ni] = __builtin_amdgcn_mfma_f32_16x16x32_bf16(ah[mi], bh[ni], acc[mi][ni], 0, 0, 0);
          acc[mi][ni] = __builtin_amdgcn_mfma_f32_16x16x32_bf16(ah[mi], bl[ni], acc[mi][ni], 0, 0, 0);
          acc[mi][ni] = __builtin_amdgcn_mfma_f32_16x16x32_bf16(al[mi], bh[ni], acc[mi][ni], 0, 0, 0);
        }
    }
  }
  #pragma unroll
  for (int ni = 0; ni < 4; ++ni) {
    const int n = n0 + wn + ni * 16 + (lane & 15);
    const float bv = bias[n];
    #pragma unroll
    for (int mi = 0; mi < 2; ++mi) {
      const int m = m0 + mi * 16 + (lane >> 4) * 4;
      #pragma unroll
      for (int r = 0; r < 4; ++r)
        emb[(size_t)(m + r) * DMODEL + n] = acc[mi][ni][r] + bv;
    }
  }
}

// ---------------------------------------------------------------------------
// gemm_emb: fp32 fallback (only if ws too small).
// ---------------------------------------------------------------------------
__global__ __launch_bounds__(256) void gemm_emb(const float* __restrict__ x,
    const float* __restrict__ W, const float* __restrict__ bias,
    float* __restrict__ emb) {
  __shared__ float As[64][64];
  __shared__ float Ws[64][132];
  const int bs = blockIdx.y;
  const int n0 = blockIdx.x * 128;
  const int t = threadIdx.x;
  const int tx = t & 15, ty = t >> 4;
  float bv[8];
  #pragma unroll
  for (int j = 0; j < 8; ++j) bv[j] = bias[n0 + 8 * tx + j];
  float acc[4][8];
  #pragma unroll
  for (int i = 0; i < 4; ++i)
    #pragma unroll
    for (int j = 0; j < 8; ++j) acc[i][j] = 0.f;
  const float* xb = x + (size_t)bs * SEQ * NVAR;
  for (int k0 = 0; k0 < SEQ; k0 += 64) {
    __syncthreads();
    {
      const float4* src = (const float4*)(xb + (size_t)k0 * NVAR);
      float4* dst = (float4*)&As[0][0];
      #pragma unroll
      for (int r = 0; r < 4; ++r) dst[t + 256 * r] = src[t + 256 * r];
    }
    #pragma unroll
    for (int r = 0; r < 8; ++r) {
      int idx = t + 256 * r;
      int k4 = idx & 15, n = idx >> 4;
      float4 wv = *(const float4*)(W + (size_t)(n0 + n) * SEQ + k0 + 4 * k4);
      Ws[4 * k4 + 0][n] = wv.x; Ws[4 * k4 + 1][n] = wv.y;
      Ws[4 * k4 + 2][n] = wv.z; Ws[4 * k4 + 3][n] = wv.w;
    }
    __syncthreads();
    #pragma unroll 8
    for (int kk = 0; kk < 64; ++kk) {
      const float4 a  = *(const float4*)&As[kk][4 * ty];
      const float4 w0 = *(const float4*)&Ws[kk][8 * tx];
      const float4 w1 = *(const float4*)&Ws[kk][8 * tx + 4];
      const float av[4] = {a.x, a.y, a.z, a.w};
      const float wv[8] = {w0.x, w0.y, w0.z, w0.w, w1.x, w1.y, w1.z, w1.w};
      #pragma unroll
      for (int i = 0; i < 4; ++i)
        #pragma unroll
        for (int j = 0; j < 8; ++j)
          acc[i][j] = fmaf(av[i], wv[j], acc[i][j]);
    }
  }
  #pragma unroll
  for (int i = 0; i < 4; ++i) {
    int row = bs * NVAR + 4 * ty + i;
    float4 o0 = make_float4(acc[i][0] + bv[0], acc[i][1] + bv[1],
                            acc[i][2] + bv[2], acc[i][3] + bv[3]);
    float4 o1 = make_float4(acc[i][4] + bv[4], acc[i][5] + bv[5],
                            acc[i][6] + bv[6], acc[i][7] + bv[7]);
    *(float4*)(emb + (size_t)row * DMODEL + n0 + 8 * tx) = o0;
    *(float4*)(emb + (size_t)row * DMODEL + n0 + 8 * tx + 4) = o1;
  }
}

// ---------------------------------------------------------------------------
// conv_et: emb fp32 -> Ehi/Elo [p][d] AND Ethi/Etlo [d][p] (LDS transpose).
// grid (8 d-tiles, 128 p-tiles) x 256.
// ---------------------------------------------------------------------------
__global__ __launch_bounds__(256) void conv_et(const float* __restrict__ emb,
    unsigned short* __restrict__ Eh, unsigned short* __restrict__ El,
    unsigned short* __restrict__ Eth, unsigned short* __restrict__ Etl) {
  __shared__ unsigned short Lh[64][72];
  __shared__ unsigned short Ll[64][72];
  const int d0 = blockIdx.x * 64;
  const int p0 = blockIdx.y * 64;
  const int t = threadIdx.x;
  #pragma unroll
  for (int q = 0; q < 2; ++q) {
    int idx = t + 256 * q;
    int r = idx >> 3, c = idx & 7;
    const float* src = emb + (size_t)(p0 + r) * DMODEL + d0 + c * 8;
    float4 v0 = *(const float4*)src;
    float4 v1 = *(const float4*)(src + 4);
    unsigned short h[8], l[8];
    const float vv[8] = {v0.x, v0.y, v0.z, v0.w, v1.x, v1.y, v1.z, v1.w};
    #pragma unroll
    for (int j = 0; j < 8; ++j) {
      h[j] = bf16_rn(vv[j]);
      l[j] = bf16_rn(vv[j] - __uint_as_float((unsigned)h[j] << 16));
    }
    size_t eo = (size_t)(p0 + r) * DMODEL + d0 + c * 8;
    *(uint4*)(Eh + eo) = *(uint4*)&h[0];
    *(uint4*)(El + eo) = *(uint4*)&l[0];
    *(uint4*)&Lh[r][c * 8] = *(uint4*)&h[0];
    *(uint4*)&Ll[r][c * 8] = *(uint4*)&l[0];
  }
  __syncthreads();
  #pragma unroll
  for (int q = 0; q < 2; ++q) {
    int idx = t + 256 * q;
    int dd = idx >> 3, pc = idx & 7;
    unsigned short h[8], l[8];
    #pragma unroll
    for (int j = 0; j < 8; ++j) {
      h[j] = Lh[pc * 8 + j][dd];
      l[j] = Ll[pc * 8 + j][dd];
    }
    size_t to = (size_t)(d0 + dd) * NPT + p0 + pc * 8;
    *(uint4*)(Eth + to) = *(uint4*)&h[0];
    *(uint4*)(Etl + to) = *(uint4*)&l[0];
  }
}

// ---------------------------------------------------------------------------
// loop_k2: persistent k-means loop.  Cooperative launch (co-residency
// guaranteed) but with a CUSTOM 2-level grid barrier instead of grid.sync():
// 8 partition counters (128B apart) -> root -> generation flag; monotonic
// counters (no reset); s_sleep(2) polling; __threadfence release/acquire.
// Phase math is verbatim R5 k12_fused + k3_update -> bitwise-identical.
// grid 256 x 256: g = bid&63 (128 points), dq = bid>>6.
// ---------------------------------------------------------------------------
__global__ __launch_bounds__(256) void loop_k2(
    const unsigned short* __restrict__ Eh, const unsigned short* __restrict__ El,
    const unsigned short* __restrict__ Eth, const unsigned short* __restrict__ Etl,
    unsigned short* __restrict__ Ch, unsigned short* __restrict__ Cl,
    float* __restrict__ cent, float* __restrict__ csq4,
    float* __restrict__ psum, float* __restrict__ pcnt,
    int* __restrict__ ids, float* __restrict__ shift2,
    float* __restrict__ out, int* __restrict__ bar) {
  __shared__ __align__(16) unsigned char smem[98304];
  __shared__ float csq_l[64];
  __shared__ int cnt_l[64];
  __shared__ int ids_l[128];
  __shared__ float red[128];
  __shared__ float cnt_s;
  __shared__ float tot_s;
  const int t = threadIdx.x;
  const int bid = blockIdx.x;
  const int w = t >> 6, lane = t & 63;
  const int g = bid & 63, dq = bid >> 6;
  const int p0 = g * 128;
  const int lrow = lane >> 3, sl8 = lane & 7;
  const int csrc = sl8 ^ lrow;
  int nbar = 0;

#define GRIDBAR() do { \
    __threadfence(); \
    __syncthreads(); \
    if (t == 0) { \
      int x_ = bid & 7; \
      int p_ = __hip_atomic_fetch_add(&bar[x_ * 32], 1, __ATOMIC_RELAXED, __HIP_MEMORY_SCOPE_AGENT); \
      if (p_ == nbar * 32 + 31) { \
        int q_ = __hip_atomic_fetch_add(&bar[256], 1, __ATOMIC_RELAXED, __HIP_MEMORY_SCOPE_AGENT); \
        if (q_ == nbar * 8 + 7) \
          __hip_atomic_store(&bar[288], nbar + 1, __ATOMIC_RELAXED, __HIP_MEMORY_SCOPE_AGENT); \
      } \
      while (__hip_atomic_load(&bar[288], __ATOMIC_RELAXED, __HIP_MEMORY_SCOPE_AGENT) <= nbar) \
        __builtin_amdgcn_s_sleep(2); \
    } \
    __syncthreads(); \
    __threadfence(); \
    nbar = nbar + 1; \
  } while (0)

#define LP_STAGE_A(B, KT) do { \
    unsigned short* bEh = (unsigned short*)(smem + (B) * 49152); \
    unsigned short* bEl = (unsigned short*)(smem + (B) * 49152 + 16384); \
    unsigned short* bCh = (unsigned short*)(smem + (B) * 49152 + 32768); \
    unsigned short* bCl = (unsigned short*)(smem + (B) * 49152 + 40960); \
    _Pragma("unroll") \
    for (int i_ = 0; i_ < 4; ++i_) { \
      const int r_ = w * 32 + i_ * 8 + lrow; \
      const size_t ga_ = (size_t)(p0 + r_) * DMODEL + (KT) + csrc * 8; \
      load_lds16(Eh + ga_, &bEh[r_ * 64 + sl8 * 8]); \
      load_lds16(El + ga_, &bEl[r_ * 64 + sl8 * 8]); \
    } \
    _Pragma("unroll") \
    for (int i_ = 0; i_ < 2; ++i_) { \
      const int r_ = w * 16 + i_ * 8 + lrow; \
      const size_t gc_ = (size_t)r_ * DMODEL + (KT) + csrc * 8; \
      load_lds16(Ch + gc_, &bCh[r_ * 64 + sl8 * 8]); \
      load_lds16(Cl + gc_, &bCl[r_ * 64 + sl8 * 8]); \
    } \
  } while (0)

#define LP_COMPUTE_A(B) do { \
    const unsigned short* bEh = (const unsigned short*)(smem + (B) * 49152); \
    const unsigned short* bEl = (const unsigned short*)(smem + (B) * 49152 + 16384); \
    const unsigned short* bCh = (const unsigned short*)(smem + (B) * 49152 + 32768); \
    const unsigned short* bCl = (const unsigned short*)(smem + (B) * 49152 + 40960); \
    _Pragma("unroll") \
    for (int kk = 0; kk < 2; ++kk) { \
      const int sl = ((kk * 4 + (lane >> 4)) ^ (lane & 7)) * 8; \
      bf16x8 eh[2], el[2], ch[4], cl[4]; \
      _Pragma("unroll") \
      for (int mi = 0; mi < 2; ++mi) { \
        int off = (w * 32 + mi * 16 + (lane & 15)) * 64 + sl; \
        eh[mi] = *(const bf16x8*)&bEh[off]; \
        el[mi] = *(const bf16x8*)&bEl[off]; \
      } \
      _Pragma("unroll") \
      for (int ni = 0; ni < 4; ++ni) { \
        int off = (ni * 16 + (lane & 15)) * 64 + sl; \
        ch[ni] = *(const bf16x8*)&bCh[off]; \
        cl[ni] = *(const bf16x8*)&bCl[off]; \
      } \
      _Pragma("unroll") \
      for (int mi = 0; mi < 2; ++mi) \
        _Pragma("unroll") \
        for (int ni = 0; ni < 4; ++ni) { \
          acc[mi][ni] = __builtin_amdgcn_mfma_f32_16x16x32_bf16(eh[mi], ch[ni], acc[mi][ni], 0, 0, 0); \
          acc[mi][ni] = __builtin_amdgcn_mfma_f32_16x16x32_bf16(eh[mi], cl[ni], acc[mi][ni], 0, 0, 0); \
          acc[mi][ni] = __builtin_amdgcn_mfma_f32_16x16x32_bf16(el[mi], ch[ni], acc[mi][ni], 0, 0, 0); \
        } \
    } \
  } while (0)

#define LP_STAGE_B(B, KT) do { \
    unsigned short* bTh = (unsigned short*)(smem + 17408 + (B) * 32768); \
    unsigned short* bTl = (unsigned short*)(smem + 17408 + (B) * 32768 + 16384); \
    _Pragma("unroll") \
    for (int i_ = 0; i_ < 4; ++i_) { \
      const int rr_ = w * 32 + i_ * 8 + lrow; \
      const size_t gt_ = (size_t)(dq * 128 + rr_) * NPT + g * 128 + (KT) + csrc * 8; \
      load_lds16(Eth + gt_, &bTh[rr_ * 64 + sl8 * 8]); \
      load_lds16(Etl + gt_, &bTl[rr_ * 64 + sl8 * 8]); \
    } \
  } while (0)

#define LP_COMPUTE_B(B, KT) do { \
    const unsigned short* bTh = (const unsigned short*)(smem + 17408 + (B) * 32768); \
    const unsigned short* bTl = (const unsigned short*)(smem + 17408 + (B) * 32768 + 16384); \
    _Pragma("unroll") \
    for (int kk = 0; kk < 2; ++kk) { \
      const int quad = lane >> 4; \
      const int poff = (KT) + kk * 32 + quad * 8; \
      bf16x8 a[4], bh[2], bl[2]; \
      _Pragma("unroll") \
      for (int mi = 0; mi < 4; ++mi) \
        a[mi] = *(const bf16x8*)&sOH[(mi * 16 + (lane & 15)) * 136 + poff]; \
      const int sl = ((kk * 4 + quad) ^ (lane & 7)) * 8; \
      _Pragma("unroll") \
      for (int ni = 0; ni < 2; ++ni) { \
        int off = (w * 32 + ni * 16 + (lane & 15)) * 64 + sl; \
        bh[ni] = *(const bf16x8*)&bTh[off]; \
        bl[ni] = *(const bf16x8*)&bTl[off]; \
      } \
      _Pragma("unroll") \
      for (int mi = 0; mi < 4; ++mi) \
        _Pragma("unroll") \
        for (int ni = 0; ni < 2; ++ni) { \
          bcc[mi][ni] = __builtin_amdgcn_mfma_f32_16x16x32_bf16(a[mi], bh[ni], bcc[mi][ni], 0, 0, 0); \
          bcc[mi][ni] = __builtin_amdgcn_mfma_f32_16x16x32_bf16(a[mi], bl[ni], bcc[mi][ni], 0, 0, 0); \
        } \
    } \
  } while (0)

  for (int it = 0; it < MAXIT; ++it) {
    // ---- phase A: assign (verbatim R5) ----
    if (t < 64) {
      csq_l[t] = csq4[t] + csq4[KC + t] + csq4[2 * KC + t] + csq4[3 * KC + t];
      cnt_l[t] = 0;
    }
    __syncthreads();   // csq loads drained; vmcnt clean

    f32x4 acc[2][4];
    #pragma unroll
    for (int i = 0; i < 2; ++i)
      #pragma unroll
      for (int j = 0; j < 4; ++j) acc[i][j] = (f32x4){0.f, 0.f, 0.f, 0.f};

    LP_STAGE_A(0, 0);
    for (int kt8 = 0; kt8 < 8; kt8 += 2) {
      LP_STAGE_A(1, (kt8 + 1) * 64);
      asm volatile("s_waitcnt vmcnt(12)" ::: "memory");
      __builtin_amdgcn_s_barrier();
      __builtin_amdgcn_sched_barrier(0);
      LP_COMPUTE_A(0);
      __builtin_amdgcn_s_barrier();
      if (kt8 + 2 < 8) {
        LP_STAGE_A(0, (kt8 + 2) * 64);
        asm volatile("s_waitcnt vmcnt(12)" ::: "memory");
      } else {
        asm volatile("s_waitcnt vmcnt(0)" ::: "memory");
      }
      __builtin_amdgcn_s_barrier();
      __builtin_amdgcn_sched_barrier(0);
      LP_COMPUTE_A(1);
      __builtin_amdgcn_s_barrier();
    }

    // argmin (verbatim R5)
    #pragma unroll
    for (int mi = 0; mi < 2; ++mi) {
      #pragma unroll
      for (int r = 0; r < 4; ++r) {
        float bv = csq_l[lane & 15] - 2.f * acc[mi][0][r];
        int bk = lane & 15;
        #pragma unroll
        for (int ni = 1; ni < 4; ++ni) {
          const int k = ni * 16 + (lane & 15);
          float v = csq_l[k] - 2.f * acc[mi][ni][r];
          if (v < bv) { bv = v; bk = k; }
        }
        #pragma unroll
        for (int m = 1; m < 16; m <<= 1) {
          float ov = __shfl_xor(bv, m, 64);
          int   ok = __shfl_xor(bk, m, 64);
          if (ov < bv || (ov == bv && ok < bk)) { bv = ov; bk = ok; }
        }
        if ((lane & 15) == 0) {
          const int p = w * 32 + mi * 16 + (lane >> 4) * 4 + r;
          ids_l[p] = bk;
          atomicAdd(&cnt_l[bk], 1);
        }
      }
    }
    __syncthreads();
    if (dq == 0 && t < 64) pcnt[g * KC + t] = (float)cnt_l[t];   // 1 store

    // ---- phase B: segsum (verbatim R5) ----
    {
      unsigned short* sOH = (unsigned short*)smem;
      LP_STAGE_B(0, 0);
      #pragma unroll
      for (int q = 0; q < 4; ++q) {
        int c = t * 4 + q;
        int cl = c >> 4, pc = c & 15;
        unsigned short v[8];
        #pragma unroll
        for (int j = 0; j < 8; ++j)
          v[j] = (ids_l[pc * 8 + j] == cl) ? (unsigned short)0x3F80 : (unsigned short)0;
        *(uint4*)&sOH[cl * 136 + pc * 8] = *(uint4*)&v[0];
      }
      LP_STAGE_B(1, 64);

      f32x4 bcc[4][2];
      #pragma unroll
      for (int i = 0; i < 4; ++i)
        #pragma unroll
        for (int j = 0; j < 2; ++j) bcc[i][j] = (f32x4){0.f, 0.f, 0.f, 0.f};

      asm volatile("s_waitcnt lgkmcnt(0)" ::: "memory");
      asm volatile("s_waitcnt vmcnt(8)" ::: "memory");
      __builtin_amdgcn_s_barrier();
      __builtin_amdgcn_sched_barrier(0);
      LP_COMPUTE_B(0, 0);
      asm volatile("s_waitcnt vmcnt(0)" ::: "memory");
      __builtin_amdgcn_s_barrier();
      __builtin_amdgcn_sched_barrier(0);
      LP_COMPUTE_B(1, 64);

      #pragma unroll
      for (int mi = 0; mi < 4; ++mi)
        #pragma unroll
        for (int ni = 0; ni < 2; ++ni) {
          const int cl = mi * 16 + (lane >> 4) * 4;
          const int d = dq * 128 + w * 32 + ni * 16 + (lane & 15);
          #pragma unroll
          for (int r = 0; r < 4; ++r)
            psum[((size_t)g * KC + cl + r) * DMODEL + d] = bcc[mi][ni][r];
        }
    }
    GRIDBAR();   // psum + pcnt visible device-wide

    // ---- phase C: update (verbatim R5 k3, 256-thread guards) ----
    {
      const int bk = bid & 63, dqq = bid >> 6;
      if (t < 128) red[t] = (t < 64) ? pcnt[(size_t)t * KC + bk] : 0.f;
      __syncthreads();
      for (int s = 64; s > 0; s >>= 1) { if (t < s) red[t] += red[t + s]; __syncthreads(); }
      if (t == 0) cnt_s = red[0];
      __syncthreads();
      const float count = cnt_s;
      float df2 = 0.f, sq = 0.f;
      if (t < 128) {
        const int d = dqq * 128 + t;
        float s = 0.f;
        #pragma unroll 16
        for (int g2 = 0; g2 < 64; ++g2)
          s += psum[((size_t)g2 * KC + bk) * DMODEL + d];
        float oldv = cent[bk * DMODEL + d];
        float newv = (count > 0.f) ? (s / fmaxf(count, 1.f)) : oldv;
        cent[bk * DMODEL + d] = newv;
        unsigned short h = bf16_rn(newv);
        Ch[bk * DMODEL + d] = h;
        Cl[bk * DMODEL + d] = bf16_rn(newv - __uint_as_float((unsigned)h << 16));
        float df = newv - oldv;
        df2 = df * df; sq = newv * newv;
      }
      if (t < 128) red[t] = df2;
      __syncthreads();
      for (int s2 = 64; s2 > 0; s2 >>= 1) { if (t < s2) red[t] += red[t + s2]; __syncthreads(); }
      if (t == 0) atomicAdd(shift2 + it, red[0]);
      __syncthreads();
      if (t < 128) red[t] = sq;
      __syncthreads();
      for (int s2 = 64; s2 > 0; s2 >>= 1) { if (t < s2) red[t] += red[t + s2]; __syncthreads(); }
      if (t == 0) csq4[dqq * KC + bk] = red[0];
    }
    GRIDBAR();   // cent/centh/centl/csq4/shift2 visible

    if (t == 0) tot_s = shift2[it];
    __syncthreads();
    if (sqrtf(tot_s) < 1e-4f) break;   // uniform across blocks
  }

  // ---- publish final ids, then finalize ----
  if (dq == 0 && t < 128) ids[p0 + t] = ids_l[t];
  GRIDBAR();
  {
    const int gtid = bid * 256 + t;
    const int n = gtid >> 3;
    const int k0 = (gtid & 7) * 8;
    const int idn = ids[n];
    float v[8];
    #pragma unroll
    for (int j = 0; j < 8; ++j) v[j] = (idn == k0 + j) ? 1.f : 0.f;
    *(float4*)(out + (size_t)n * KC + k0)     = make_float4(v[0], v[1], v[2], v[3]);
    *(float4*)(out + (size_t)n * KC + k0 + 4) = make_float4(v[4], v[5], v[6], v[7]);
    if (gtid < KC * DMODEL) out[NPT * KC + gtid] = cent[gtid];
  }
#undef GRIDBAR
#undef LP_STAGE_A
#undef LP_COMPUTE_A
#undef LP_STAGE_B
#undef LP_COMPUTE_B
}

// ---------------------------------------------------------------------------
// Fallback per-iteration kernels (used only if cooperative launch fails).
// ---------------------------------------------------------------------------
__global__ __launch_bounds__(256) void k12_fused(
    const unsigned short* __restrict__ Eh, const unsigned short* __restrict__ El,
    const unsigned short* __restrict__ Eth, const unsigned short* __restrict__ Etl,
    const unsigned short* __restrict__ Ch, const unsigned short* __restrict__ Cl,
    const float* __restrict__ csq4, const int* __restrict__ done,
    int* __restrict__ ids, float* __restrict__ pcnt, float* __restrict__ psum) {
  if (*done) return;
  __shared__ __align__(16) unsigned char smem[98304];
  __shared__ float csq_l[64];
  __shared__ int cnt_l[64];
  __shared__ int ids_l[128];
  const int t = threadIdx.x;
  const int w = t >> 6, lane = t & 63;
  const int g = blockIdx.x & 63, dq = blockIdx.x >> 6;
  const int p0 = g * 128;
  const int lrow = lane >> 3, sl8 = lane & 7;
  const int csrc = sl8 ^ lrow;

  if (t < 64) {
    csq_l[t] = csq4[t] + csq4[KC + t] + csq4[2 * KC + t] + csq4[3 * KC + t];
    cnt_l[t] = 0;
  }
  __syncthreads();

#define STAGE_A(B, KT) do { \
    unsigned short* bEh = (unsigned short*)(smem + (B) * 49152); \
    unsigned short* bEl = (unsigned short*)(smem + (B) * 49152 + 16384); \
    unsigned short* bCh = (unsigned short*)(smem + (B) * 49152 + 32768); \
    unsigned short* bCl = (unsigned short*)(smem + (B) * 49152 + 40960); \
    _Pragma("unroll") \
    for (int i_ = 0; i_ < 4; ++i_) { \
      const int r_ = w * 32 + i_ * 8 + lrow; \
      const size_t ga_ = (size_t)(p0 + r_) * DMODEL + (KT) + csrc * 8; \
      load_lds16(Eh + ga_, &bEh[r_ * 64 + sl8 * 8]); \
      load_lds16(El + ga_, &bEl[r_ * 64 + sl8 * 8]); \
    } \
    _Pragma("unroll") \
    for (int i_ = 0; i_ < 2; ++i_) { \
      const int r_ = w * 16 + i_ * 8 + lrow; \
      const size_t gc_ = (size_t)r_ * DMODEL + (KT) + csrc * 8; \
      load_lds16(Ch + gc_, &bCh[r_ * 64 + sl8 * 8]); \
      load_lds16(Cl + gc_, &bCl[r_ * 64 + sl8 * 8]); \
    } \
  } while (0)

#define COMPUTE_A(B) do { \
    const unsigned short* bEh = (const unsigned short*)(smem + (B) * 49152); \
    const unsigned short* bEl = (const unsigned short*)(smem + (B) * 49152 + 16384); \
    const unsigned short* bCh = (const unsigned short*)(smem + (B) * 49152 + 32768); \
    const unsigned short* bCl = (const unsigned short*)(smem + (B) * 49152 + 40960); \
    _Pragma("unroll") \
    for (int kk = 0; kk < 2; ++kk) { \
      const int sl = ((kk * 4 + (lane >> 4)) ^ (lane & 7)) * 8; \
      bf16x8 eh[2], el[2], ch[4], cl[4]; \
      _Pragma("unroll") \
      for (int mi = 0; mi < 2; ++mi) { \
        int off = (w * 32 + mi * 16 + (lane & 15)) * 64 + sl; \
        eh[mi] = *(const bf16x8*)&bEh[off]; \
        el[mi] = *(const bf16x8*)&bEl[off]; \
      } \
      _Pragma("unroll") \
      for (int ni = 0; ni < 4; ++ni) { \
        int off = (ni * 16 + (lane & 15)) * 64 + sl; \
        ch[ni] = *(const bf16x8*)&bCh[off]; \
        cl[ni] = *(const bf16x8*)&bCl[off]; \
      } \
      _Pragma("unroll") \
      for (int mi = 0; mi < 2; ++mi) \
        _Pragma("unroll") \
        for (int ni = 0; ni < 4; ++ni) { \
          acc[mi][ni] = __builtin_amdgcn_mfma_f32_16x16x32_bf16(eh[mi], ch[ni], acc[mi][ni], 0, 0, 0); \
          acc[mi][ni] = __builtin_amdgcn_mfma_f32_16x16x32_bf16(eh[mi], cl[ni], acc[mi][ni], 0, 0, 0); \
          acc[mi][ni] = __builtin_amdgcn_mfma_f32_16x16x32_bf16(el[mi], ch[ni], acc[mi][ni], 0, 0, 0); \
        } \
    } \
  } while (0)

  f32x4 acc[2][4];
  #pragma unroll
  for (int i = 0; i < 2; ++i)
    #pragma unroll
    for (int j = 0; j < 4; ++j) acc[i][j] = (f32x4){0.f, 0.f, 0.f, 0.f};

  STAGE_A(0, 0);
  for (int kt8 = 0; kt8 < 8; kt8 += 2) {
    STAGE_A(1, (kt8 + 1) * 64);
    asm volatile("s_waitcnt vmcnt(12)" ::: "memory");
    __builtin_amdgcn_s_barrier();
    __builtin_amdgcn_sched_barrier(0);
    COMPUTE_A(0);
    __builtin_amdgcn_s_barrier();
    if (kt8 + 2 < 8) {
      STAGE_A(0, (kt8 + 2) * 64);
      asm volatile("s_waitcnt vmcnt(12)" ::: "memory");
    } else {
      asm volatile("s_waitcnt vmcnt(0)" ::: "memory");
    }
    __builtin_amdgcn_s_barrier();
    __builtin_amdgcn_sched_barrier(0);
    COMPUTE_A(1);
    __builtin_amdgcn_s_barrier();
  }

  #pragma unroll
  for (int mi = 0; mi < 2; ++mi) {
    #pragma unroll
    for (int r = 0; r < 4; ++r) {
      float bv = csq_l[lane & 15] - 2.f * acc[mi][0][r];
      int bk = lane & 15;
      #pragma unroll
      for (int ni = 1; ni < 4; ++ni) {
        const int k = ni * 16 + (lane & 15);
        float v = csq_l[k] - 2.f * acc[mi][ni][r];
        if (v < bv) { bv = v; bk = k; }
      }
      #pragma unroll
      for (int m = 1; m < 16; m <<= 1) {
        float ov = __shfl_xor(bv, m, 64);
        int   ok = __shfl_xor(bk, m, 64);
        if (ov < bv || (ov == bv && ok < bk)) { bv = ov; bk = ok; }
      }
      if ((lane & 15) == 0) {
        const int p = w * 32 + mi * 16 + (lane >> 4) * 4 + r;
        ids_l[p] = bk;
        atomicAdd(&cnt_l[bk], 1);
      }
    }
  }
  __syncthreads();
  if (dq == 0) {
    if (t < 128) ids[p0 + t] = ids_l[t];
    if (t < 64) pcnt[g * KC + t] = (float)cnt_l[t];
  }

#define STAGE_B(B, KT) do { \
    unsigned short* bTh = (unsigned short*)(smem + 17408 + (B) * 32768); \
    unsigned short* bTl = (unsigned short*)(smem + 17408 + (B) * 32768 + 16384); \
    _Pragma("unroll") \
    for (int i_ = 0; i_ < 4; ++i_) { \
      const int rr_ = w * 32 + i_ * 8 + lrow; \
      const size_t gt_ = (size_t)(dq * 128 + rr_) * NPT + g * 128 + (KT) + csrc * 8; \
      load_lds16(Eth + gt_, &bTh[rr_ * 64 + sl8 * 8]); \
      load_lds16(Etl + gt_, &bTl[rr_ * 64 + sl8 * 8]); \
    } \
  } while (0)

#define COMPUTE_B(B, KT) do { \
    const unsigned short* bTh = (const unsigned short*)(smem + 17408 + (B) * 32768); \
    const unsigned short* bTl = (const unsigned short*)(smem + 17408 + (B) * 32768 + 16384); \
    _Pragma("unroll") \
    for (int kk = 0; kk < 2; ++kk) { \
      const int quad = lane >> 4; \
      const int poff = (KT) + kk * 32 + quad * 8; \
      bf16x8 a[4], bh[2], bl[2]; \
      _Pragma("unroll") \
      for (int mi = 0; mi < 4; ++mi) \
        a[mi] = *(const bf16x8*)&sOH[(mi * 16 + (lane & 15)) * 136 + poff]; \
      const int sl = ((kk * 4 + quad) ^ (lane & 7)) * 8; \
      _Pragma("unroll") \
      for (int ni = 0; ni < 2; ++ni) { \
        int off = (w * 32 + ni * 16 + (lane & 15)) * 64 + sl; \
        bh[ni] = *(const bf16x8*)&bTh[off]; \
        bl[ni] = *(const bf16x8*)&bTl[off]; \
      } \
      _Pragma("unroll") \
      for (int mi = 0; mi < 4; ++mi) \
        _Pragma("unroll") \
        for (int ni = 0; ni < 2; ++ni) { \
          bcc[mi][ni] = __builtin_amdgcn_mfma_f32_16x16x32_bf16(a[mi], bh[ni], bcc[mi][ni], 0, 0, 0); \
          bcc[mi][ni] = __builtin_amdgcn_mfma_f32_16x16x32_bf16(a[mi], bl[ni], bcc[mi][ni], 0, 0, 0); \
        } \
    } \
  } while (0)

  {
    unsigned short* sOH = (unsigned short*)smem;
    STAGE_B(0, 0);
    #pragma unroll
    for (int q = 0; q < 4; ++q) {
      int c = t * 4 + q;
      int cl = c >> 4, pc = c & 15;
      unsigned short v[8];
      #pragma unroll
      for (int j = 0; j < 8; ++j)
        v[j] = (ids_l[pc * 8 + j] == cl) ? (unsigned short)0x3F80 : (unsigned short)0;
      *(uint4*)&sOH[cl * 136 + pc * 8] = *(uint4*)&v[0];
    }
    STAGE_B(1, 64);

    f32x4 bcc[4][2];
    #pragma unroll
    for (int i = 0; i < 4; ++i)
      #pragma unroll
      for (int j = 0; j < 2; ++j) bcc[i][j] = (f32x4){0.f, 0.f, 0.f, 0.f};

    asm volatile("s_waitcnt lgkmcnt(0)" ::: "memory");
    asm volatile("s_waitcnt vmcnt(8)" ::: "memory");
    __builtin_amdgcn_s_barrier();
    __builtin_amdgcn_sched_barrier(0);
    COMPUTE_B(0, 0);
    asm volatile("s_waitcnt vmcnt(0)" ::: "memory");
    __builtin_amdgcn_s_barrier();
    __builtin_amdgcn_sched_barrier(0);
    COMPUTE_B(1, 64);

    #pragma unroll
    for (int mi = 0; mi < 4; ++mi)
      #pragma unroll
      for (int ni = 0; ni < 2; ++ni) {
        const int cl = mi * 16 + (lane >> 4) * 4;
        const int d = dq * 128 + w * 32 + ni * 16 + (lane & 15);
        #pragma unroll
        for (int r = 0; r < 4; ++r)
          psum[((size_t)g * KC + cl + r) * DMODEL + d] = bcc[mi][ni][r];
      }
  }
#undef STAGE_A
#undef COMPUTE_A
#undef STAGE_B
#undef COMPUTE_B
}

__global__ __launch_bounds__(128) void k3_update(float* __restrict__ cent,
    unsigned short* __restrict__ centh, unsigned short* __restrict__ centl,
    const float* __restrict__ psum, const float* __restrict__ pcnt,
    int* __restrict__ done, float* __restrict__ csq4,
    float* __restrict__ shift2, int* __restrict__ ticket, int iter) {
  if (*done) return;
  const int bk = blockIdx.x & 63, dq = blockIdx.x >> 6;
  const int t = threadIdx.x;
  __shared__ float red[128];
  __shared__ float cnt_s;
  red[t] = (t < 64) ? pcnt[(size_t)t * KC + bk] : 0.f;
  __syncthreads();
  for (int s = 64; s > 0; s >>= 1) { if (t < s) red[t] += red[t + s]; __syncthreads(); }
  if (t == 0) cnt_s = red[0];
  __syncthreads();
  const float count = cnt_s;
  const int d = dq * 128 + t;
  float s = 0.f;
  #pragma unroll 16
  for (int g = 0; g < 64; ++g)
    s += psum[((size_t)g * KC + bk) * DMODEL + d];
  float oldv = cent[bk * DMODEL + d];
  float newv = (count > 0.f) ? (s / fmaxf(count, 1.f)) : oldv;
  cent[bk * DMODEL + d] = newv;
  unsigned short h = bf16_rn(newv);
  centh[bk * DMODEL + d] = h;
  centl[bk * DMODEL + d] = bf16_rn(newv - __uint_as_float((unsigned)h << 16));
  float df = newv - oldv;
  red[t] = df * df; __syncthreads();
  for (int s2 = 64; s2 > 0; s2 >>= 1) { if (t < s2) red[t] += red[t + s2]; __syncthreads(); }
  float tot_sh = red[0]; __syncthreads();
  red[t] = newv * newv; __syncthreads();
  for (int s2 = 64; s2 > 0; s2 >>= 1) { if (t < s2) red[t] += red[t + s2]; __syncthreads(); }
  if (t == 0) {
    csq4[dq * KC + bk] = red[0];
    atomicAdd(shift2 + iter, tot_sh);
    __threadfence();
    int tk = atomicAdd(ticket + iter, 1);
    if (tk == 255) {
      float tot = atomicAdd(shift2 + iter, 0.f);
      if (sqrtf(tot) < 1e-4f) *done = 1;
    }
  }
}

__global__ __launch_bounds__(256) void finalize_k(const int* __restrict__ ids,
    const float* __restrict__ cent, float* __restrict__ out) {
  int t = blockIdx.x * 256 + threadIdx.x;
  if (t < NPT * KC) {
    int n = t >> 6, k = t & 63;
    out[t] = (ids[n] == k) ? 1.f : 0.f;
  } else {
    int i = t - NPT * KC;
    if (i < KC * DMODEL) out[NPT * KC + i] = cent[i];
  }
}

// ---------------------------------------------------------------------------
extern "C" void kernel_launch(void* const* d_in, const int* in_sizes, int n_in,
                              void* d_out, int out_size, void* d_ws, size_t ws_size,
                              hipStream_t stream) {
  const float* x    = (const float*)d_in[0];
  const float* W    = (const float*)d_in[1];
  const float* bias = (const float*)d_in[2];
  const float* c0   = (const float*)d_in[3];
  float* out = (float*)d_out;
  float* emb_out = out + NPT * KC + KC * DMODEL;

  char* ws = (char*)d_ws;
  // loop phase (live after gemm finishes):
  unsigned short* Ehi  = (unsigned short*)(ws + 0);
  unsigned short* Elo  = (unsigned short*)(ws + 8388608);
  unsigned short* Eth  = (unsigned short*)(ws + 16777216);
  unsigned short* Etl  = (unsigned short*)(ws + 25165824);
  float* psum    = (float*)(ws + 33554432);
  float* cent    = (float*)(ws + 41943040);
  unsigned short* centh = (unsigned short*)(ws + 42074112);
  unsigned short* centl = (unsigned short*)(ws + 42139648);
  float* csq4    = (float*)(ws + 42205184);   // 4*64 floats
  float* shift2  = (float*)(ws + 42206208);
  int*   ticket  = (int*)(ws + 42206272);
  int*   done_f  = (int*)(ws + 42206336);
  float* pcnt    = (float*)(ws + 42206400);   // 64*64 floats
  int*   ids     = (int*)(ws + 42271936);     // 8192 ints -> ends 42304704
  int*   bar     = (int*)(ws + 42304704);     // 320 ints barrier state
  // gemm phase (aliases loop region; dead before init_k/conv_et run):
  unsigned short* Xh = (unsigned short*)(ws + 0);
  unsigned short* Xl = (unsigned short*)(ws + 33554432);
  unsigned short* Wh = (unsigned short*)(ws + 67108864);
  unsigned short* Wl = (unsigned short*)(ws + 69206016);
  const size_t need_fast = 71303168;
  (void)n_in; (void)in_sizes; (void)out_size;

  if (ws_size >= need_fast) {
    conv_w<<<1024, 256, 0, stream>>>(W, Wh, Wl);
    conv_x<<<dim3(32, BSZ), 256, 0, stream>>>(x, Xh, Xl);
    gemm_mfma<<<dim3(256, 2), 256, 0, stream>>>(Xh, Xl, Wh, Wl, bias, emb_out);
  } else {
    gemm_emb<<<dim3(4, BSZ), 256, 0, stream>>>(x, W, bias, emb_out);
  }
  init_k<<<KC, 256, 0, stream>>>(c0, cent, centh, centl, csq4, done_f, shift2,
                                 ticket, bar);
  conv_et<<<dim3(8, 128), 256, 0, stream>>>(emb_out, Ehi, Elo, Eth, Etl);

  void* cargs[] = {(void*)&Ehi, (void*)&Elo, (void*)&Eth, (void*)&Etl,
                   (void*)&centh, (void*)&centl, (void*)&cent, (void*)&csq4,
                   (void*)&psum, (void*)&pcnt, (void*)&ids, (void*)&shift2,
                   (void*)&out, (void*)&bar};
  hipError_t cerr = hipLaunchCooperativeKernel(loop_k2, dim3(256), dim3(256),
                                               cargs, 0u, stream);
  if (cerr != hipSuccess) {
    // fallback: per-iteration dispatches (identical math)
    for (int it = 0; it < MAXIT; ++it) {
      k12_fused<<<256, 256, 0, stream>>>(Ehi, Elo, Eth, Etl, centh, centl,
                                         csq4, done_f, ids, pcnt, psum);
      k3_update<<<256, 128, 0, stream>>>(cent, centh, centl, psum, pcnt, done_f,
                                         csq4, shift2, ticket, it);
    }
    finalize_k<<<2176, 256, 0, stream>>>(ids, cent, out);
  }
}

// Round 7
// 482.838 us; speedup vs baseline: 2.6491x; 2.6491x over previous
//
#include <hip/hip_runtime.h>

#define SEQ 2048
#define NVAR 64
#define DMODEL 512
#define BSZ 128
#define KC 64
#define NPT (BSZ*NVAR)   /* 8192 points */
#define MAXIT 10

typedef __bf16 bf16x8 __attribute__((ext_vector_type(8)));
typedef float f32x4 __attribute__((ext_vector_type(4)));

__device__ __forceinline__ void load_lds16(const void* g, void* l) {
  __builtin_amdgcn_global_load_lds((const __attribute__((address_space(1))) void*)g,
                                   (__attribute__((address_space(3))) void*)l, 16, 0, 0);
}

__device__ __forceinline__ unsigned short bf16_rn(float x) {
  unsigned int u = __float_as_uint(x);
  u += 0x7fffu + ((u >> 16) & 1u);
  return (unsigned short)(u >> 16);
}

// ---------------------------------------------------------------------------
// prep_k: conv_x (all 4096 blocks) + conv_w (blocks 0..1023).
// conv_x: x[bs][k][v] -> Xh/Xl [bs*64+v][k]; conv_w: W fp32 -> Wh/Wl.
// grid 4096 x 256 (flat; bx = fid&31 k-tile, bs = fid>>5).
// ---------------------------------------------------------------------------
__global__ __launch_bounds__(256) void prep_k(const float* __restrict__ x,
    unsigned short* __restrict__ Xh, unsigned short* __restrict__ Xl,
    const float* __restrict__ W, unsigned short* __restrict__ Wh,
    unsigned short* __restrict__ Wl) {
  __shared__ float tile[64 * 65];
  const int fid = blockIdx.x;
  const int t = threadIdx.x;

  // conv_w role (first 1024 blocks; independent of conv_x work)
  if (fid < 1024) {
    int i = (fid * 256 + t) * 4;
    float4 v = *(const float4*)(W + i);
    ushort4 h, l;
    h.x = bf16_rn(v.x); l.x = bf16_rn(v.x - __uint_as_float((unsigned)h.x << 16));
    h.y = bf16_rn(v.y); l.y = bf16_rn(v.y - __uint_as_float((unsigned)h.y << 16));
    h.z = bf16_rn(v.z); l.z = bf16_rn(v.z - __uint_as_float((unsigned)h.z << 16));
    h.w = bf16_rn(v.w); l.w = bf16_rn(v.w - __uint_as_float((unsigned)h.w << 16));
    *(ushort4*)(Wh + i) = h;
    *(ushort4*)(Wl + i) = l;
  }

  // conv_x role (all blocks)
  const int k0 = (fid & 31) * 64;
  const int bs = fid >> 5;
  const float* xb = x + (size_t)bs * SEQ * NVAR + (size_t)k0 * NVAR;
  #pragma unroll
  for (int p = 0; p < 4; ++p) {
    int idx = t + 256 * p;
    int row = idx >> 4, c4 = (idx & 15) * 4;
    float4 v = *(const float4*)(xb + row * NVAR + c4);
    tile[row * 65 + c4 + 0] = v.x; tile[row * 65 + c4 + 1] = v.y;
    tile[row * 65 + c4 + 2] = v.z; tile[row * 65 + c4 + 3] = v.w;
  }
  __syncthreads();
  const int v = t >> 2;
  const int kc = (t & 3) * 16;
  unsigned short h[16], l[16];
  #pragma unroll
  for (int j = 0; j < 16; ++j) {
    float f = tile[(kc + j) * 65 + v];
    h[j] = bf16_rn(f);
    l[j] = bf16_rn(f - __uint_as_float((unsigned)h[j] << 16));
  }
  size_t off = (size_t)(bs * 64 + v) * SEQ + k0 + kc;
  *(uint4*)(Xh + off)     = *(uint4*)&h[0];
  *(uint4*)(Xh + off + 8) = *(uint4*)&h[8];
  *(uint4*)(Xl + off)     = *(uint4*)&l[0];
  *(uint4*)(Xl + off + 8) = *(uint4*)&l[8];
}

// ---------------------------------------------------------------------------
// gemm_mfma: emb = Xt·W^T + b, bf16x3 split.  Tile 32m x 256n, BK=64.
// grid (256 m, 2 n).
// ---------------------------------------------------------------------------
__global__ __launch_bounds__(256) void gemm_mfma(
    const unsigned short* __restrict__ Ah, const unsigned short* __restrict__ Al,
    const unsigned short* __restrict__ Bh, const unsigned short* __restrict__ Bl,
    const float* __restrict__ bias, float* __restrict__ emb) {
  __shared__ unsigned short sAh[32 * 64] __attribute__((aligned(16)));
  __shared__ unsigned short sAl[32 * 64] __attribute__((aligned(16)));
  __shared__ unsigned short sBh[256 * 64] __attribute__((aligned(16)));
  __shared__ unsigned short sBl[256 * 64] __attribute__((aligned(16)));
  const int t = threadIdx.x;
  const int w = t >> 6, lane = t & 63;
  const int m0 = blockIdx.x * 32;
  const int n0 = blockIdx.y * 256;
  const int wn = w * 64;
  const int lrow = lane >> 3, sl8 = lane & 7;
  const int csrc = sl8 ^ lrow;

  f32x4 acc[2][4];
  #pragma unroll
  for (int i = 0; i < 2; ++i)
    #pragma unroll
    for (int j = 0; j < 4; ++j) acc[i][j] = (f32x4){0.f, 0.f, 0.f, 0.f};

  for (int kt = 0; kt < SEQ; kt += 64) {
    __syncthreads();
    {
      const int r = w * 8 + lrow;          // A rows 0..31
      const size_t ga = (size_t)(m0 + r) * SEQ + kt + csrc * 8;
      load_lds16(Ah + ga, &sAh[r * 64 + sl8 * 8]);
      load_lds16(Al + ga, &sAl[r * 64 + sl8 * 8]);
    }
    #pragma unroll
    for (int i = 0; i < 8; ++i) {
      const int r = w * 64 + i * 8 + lrow; // B rows 0..255
      const size_t gb = (size_t)(n0 + r) * SEQ + kt + csrc * 8;
      load_lds16(Bh + gb, &sBh[r * 64 + sl8 * 8]);
      load_lds16(Bl + gb, &sBl[r * 64 + sl8 * 8]);
    }
    __syncthreads();
    #pragma unroll
    for (int kk = 0; kk < 2; ++kk) {
      const int sl = ((kk * 4 + (lane >> 4)) ^ (lane & 7)) * 8;
      bf16x8 ah[2], al[2], bh[4], bl[4];
      #pragma unroll
      for (int mi = 0; mi < 2; ++mi) {
        int off = (mi * 16 + (lane & 15)) * 64 + sl;
        ah[mi] = *(const bf16x8*)&sAh[off];
        al[mi] = *(const bf16x8*)&sAl[off];
      }
      #pragma unroll
      for (int ni = 0; ni < 4; ++ni) {
        int off = (wn + ni * 16 + (lane & 15)) * 64 + sl;
        bh[ni] = *(const bf16x8*)&sBh[off];
        bl[ni] = *(const bf16x8*)&sBl[off];
      }
      #pragma unroll
      for (int mi = 0; mi < 2; ++mi)
        #pragma unroll
        for (int ni = 0; ni < 4; ++ni) {
          acc[mi][ni] = __builtin_amdgcn_mfma_f32_16x16x32_bf16(ah[mi], bh[ni], acc[mi][ni], 0, 0, 0);
          acc[mi][ni] = __builtin_amdgcn_mfma_f32_16x16x32_bf16(ah[mi], bl[ni], acc[mi][ni], 0, 0, 0);
          acc[mi][ni] = __builtin_amdgcn_mfma_f32_16x16x32_bf16(al[mi], bh[ni], acc[mi][ni], 0, 0, 0);
        }
    }
  }
  #pragma unroll
  for (int ni = 0; ni < 4; ++ni) {
    const int n = n0 + wn + ni * 16 + (lane & 15);
    const float bv = bias[n];
    #pragma unroll
    for (int mi = 0; mi < 2; ++mi) {
      const int m = m0 + mi * 16 + (lane >> 4) * 4;
      #pragma unroll
      for (int r = 0; r < 4; ++r)
        emb[(size_t)(m + r) * DMODEL + n] = acc[mi][ni][r] + bv;
    }
  }
}

// ---------------------------------------------------------------------------
// gemm_emb: fp32 fallback (only if ws too small).
// ---------------------------------------------------------------------------
__global__ __launch_bounds__(256) void gemm_emb(const float* __restrict__ x,
    const float* __restrict__ W, const float* __restrict__ bias,
    float* __restrict__ emb) {
  __shared__ float As[64][64];
  __shared__ float Ws[64][132];
  const int bs = blockIdx.y;
  const int n0 = blockIdx.x * 128;
  const int t = threadIdx.x;
  const int tx = t & 15, ty = t >> 4;
  float bv[8];
  #pragma unroll
  for (int j = 0; j < 8; ++j) bv[j] = bias[n0 + 8 * tx + j];
  float acc[4][8];
  #pragma unroll
  for (int i = 0; i < 4; ++i)
    #pragma unroll
    for (int j = 0; j < 8; ++j) acc[i][j] = 0.f;
  const float* xb = x + (size_t)bs * SEQ * NVAR;
  for (int k0 = 0; k0 < SEQ; k0 += 64) {
    __syncthreads();
    {
      const float4* src = (const float4*)(xb + (size_t)k0 * NVAR);
      float4* dst = (float4*)&As[0][0];
      #pragma unroll
      for (int r = 0; r < 4; ++r) dst[t + 256 * r] = src[t + 256 * r];
    }
    #pragma unroll
    for (int r = 0; r < 8; ++r) {
      int idx = t + 256 * r;
      int k4 = idx & 15, n = idx >> 4;
      float4 wv = *(const float4*)(W + (size_t)(n0 + n) * SEQ + k0 + 4 * k4);
      Ws[4 * k4 + 0][n] = wv.x; Ws[4 * k4 + 1][n] = wv.y;
      Ws[4 * k4 + 2][n] = wv.z; Ws[4 * k4 + 3][n] = wv.w;
    }
    __syncthreads();
    #pragma unroll 8
    for (int kk = 0; kk < 64; ++kk) {
      const float4 a  = *(const float4*)&As[kk][4 * ty];
      const float4 w0 = *(const float4*)&Ws[kk][8 * tx];
      const float4 w1 = *(const float4*)&Ws[kk][8 * tx + 4];
      const float av[4] = {a.x, a.y, a.z, a.w};
      const float wv[8] = {w0.x, w0.y, w0.z, w0.w, w1.x, w1.y, w1.z, w1.w};
      #pragma unroll
      for (int i = 0; i < 4; ++i)
        #pragma unroll
        for (int j = 0; j < 8; ++j)
          acc[i][j] = fmaf(av[i], wv[j], acc[i][j]);
    }
  }
  #pragma unroll
  for (int i = 0; i < 4; ++i) {
    int row = bs * NVAR + 4 * ty + i;
    float4 o0 = make_float4(acc[i][0] + bv[0], acc[i][1] + bv[1],
                            acc[i][2] + bv[2], acc[i][3] + bv[3]);
    float4 o1 = make_float4(acc[i][4] + bv[4], acc[i][5] + bv[5],
                            acc[i][6] + bv[6], acc[i][7] + bv[7]);
    *(float4*)(emb + (size_t)row * DMODEL + n0 + 8 * tx) = o0;
    *(float4*)(emb + (size_t)row * DMODEL + n0 + 8 * tx + 4) = o1;
  }
}

// ---------------------------------------------------------------------------
// conv_et: emb fp32 -> Ehi/Elo [p][d] AND Eth/Etl [d][p] (LDS transpose),
// PLUS init role (flat block id < 64): cent/centh/centl/csq4/flags for k=fid.
// Runs after gemm, so writing cent (aliases gemm's Xl region) is safe.
// grid (8 d-tiles, 128 p-tiles) x 256.
// ---------------------------------------------------------------------------
__global__ __launch_bounds__(256) void conv_et(const float* __restrict__ emb,
    unsigned short* __restrict__ Eh, unsigned short* __restrict__ El,
    unsigned short* __restrict__ Eth, unsigned short* __restrict__ Etl,
    const float* __restrict__ c0, float* __restrict__ cent,
    unsigned short* __restrict__ centh, unsigned short* __restrict__ centl,
    float* __restrict__ csq4, int* __restrict__ done,
    float* __restrict__ shift2, int* __restrict__ ticket) {
  __shared__ unsigned short Lh[64][72];
  __shared__ unsigned short Ll[64][72];
  __shared__ float red[256];
  const int d0 = blockIdx.x * 64;
  const int p0 = blockIdx.y * 64;
  const int t = threadIdx.x;
  #pragma unroll
  for (int q = 0; q < 2; ++q) {
    int idx = t + 256 * q;
    int r = idx >> 3, c = idx & 7;
    const float* src = emb + (size_t)(p0 + r) * DMODEL + d0 + c * 8;
    float4 v0 = *(const float4*)src;
    float4 v1 = *(const float4*)(src + 4);
    unsigned short h[8], l[8];
    const float vv[8] = {v0.x, v0.y, v0.z, v0.w, v1.x, v1.y, v1.z, v1.w};
    #pragma unroll
    for (int j = 0; j < 8; ++j) {
      h[j] = bf16_rn(vv[j]);
      l[j] = bf16_rn(vv[j] - __uint_as_float((unsigned)h[j] << 16));
    }
    size_t eo = (size_t)(p0 + r) * DMODEL + d0 + c * 8;
    *(uint4*)(Eh + eo) = *(uint4*)&h[0];
    *(uint4*)(El + eo) = *(uint4*)&l[0];
    *(uint4*)&Lh[r][c * 8] = *(uint4*)&h[0];
    *(uint4*)&Ll[r][c * 8] = *(uint4*)&l[0];
  }
  __syncthreads();
  #pragma unroll
  for (int q = 0; q < 2; ++q) {
    int idx = t + 256 * q;
    int dd = idx >> 3, pc = idx & 7;
    unsigned short h[8], l[8];
    #pragma unroll
    for (int j = 0; j < 8; ++j) {
      h[j] = Lh[pc * 8 + j][dd];
      l[j] = Ll[pc * 8 + j][dd];
    }
    size_t to = (size_t)(d0 + dd) * NPT + p0 + pc * 8;
    *(uint4*)(Eth + to) = *(uint4*)&h[0];
    *(uint4*)(Etl + to) = *(uint4*)&l[0];
  }

  // init role: flat block id < 64 handles centroid k = fid.
  const int fid = blockIdx.x + 8 * blockIdx.y;
  if (fid < KC) {
    const int k = fid;
    float v0, v1;
    {
      int d = t;                       // 0..255 (quarters 0,1)
      v0 = c0[k * DMODEL + d];
      cent[k * DMODEL + d] = v0;
      unsigned short h = bf16_rn(v0);
      centh[k * DMODEL + d] = h;
      centl[k * DMODEL + d] = bf16_rn(v0 - __uint_as_float((unsigned)h << 16));
    }
    {
      int d = t + 256;                 // 256..511 (quarters 2,3)
      v1 = c0[k * DMODEL + d];
      cent[k * DMODEL + d] = v1;
      unsigned short h = bf16_rn(v1);
      centh[k * DMODEL + d] = h;
      centl[k * DMODEL + d] = bf16_rn(v1 - __uint_as_float((unsigned)h << 16));
    }
    __syncthreads();
    red[t] = v0 * v0; __syncthreads();
    for (int s = 64; s > 0; s >>= 1) { if ((t & 127) < s) red[t] += red[t + s]; __syncthreads(); }
    if (t == 0)   csq4[0 * KC + k] = red[0];
    if (t == 128) csq4[1 * KC + k] = red[128];
    __syncthreads();
    red[t] = v1 * v1; __syncthreads();
    for (int s = 64; s > 0; s >>= 1) { if ((t & 127) < s) red[t] += red[t + s]; __syncthreads(); }
    if (t == 0)   csq4[2 * KC + k] = red[0];
    if (t == 128) csq4[3 * KC + k] = red[128];
    if (k == 0 && t < MAXIT) { shift2[t] = 0.f; ticket[t] = 0; }
    if (k == 0 && t == 31) *done = 0;
  }
}

// ---------------------------------------------------------------------------
// k1 assign: D[p][k] = csq[k] - 2*E·cent^T (3-term bf16 MFMA), argmin, counts.
// grid 256 (32 p each), block 128 (2 waves; wave = 16p x 64k).  [R2 verbatim]
// ---------------------------------------------------------------------------
__global__ __launch_bounds__(128) void k1_assign(
    const unsigned short* __restrict__ Eh, const unsigned short* __restrict__ El,
    const unsigned short* __restrict__ Ch, const unsigned short* __restrict__ Cl,
    const float* __restrict__ csq4, const int* __restrict__ done,
    int* __restrict__ ids, float* __restrict__ pcnt) {
  if (*done) return;
  __shared__ unsigned short sEh[32 * 64] __attribute__((aligned(16)));
  __shared__ unsigned short sEl[32 * 64] __attribute__((aligned(16)));
  __shared__ unsigned short sCh[64 * 64] __attribute__((aligned(16)));
  __shared__ unsigned short sCl[64 * 64] __attribute__((aligned(16)));
  __shared__ float Dmat[32][65];
  __shared__ float csq_l[64];
  __shared__ int cnt_l[64];
  const int t = threadIdx.x;
  const int w = t >> 6, lane = t & 63;
  const int p0 = blockIdx.x * 32;
  const int lrow = lane >> 3, sl8 = lane & 7;
  const int csrc = sl8 ^ lrow;
  if (t < 64) {
    csq_l[t] = csq4[t] + csq4[KC + t] + csq4[2 * KC + t] + csq4[3 * KC + t];
    cnt_l[t] = 0;
  }

  f32x4 acc[4];
  #pragma unroll
  for (int j = 0; j < 4; ++j) acc[j] = (f32x4){0.f, 0.f, 0.f, 0.f};

  for (int kt = 0; kt < DMODEL; kt += 64) {
    __syncthreads();
    #pragma unroll
    for (int i = 0; i < 2; ++i) {          // E rows 0..31 (16/wave)
      const int r = w * 16 + i * 8 + lrow;
      const size_t ga = (size_t)(p0 + r) * DMODEL + kt + csrc * 8;
      load_lds16(Eh + ga, &sEh[r * 64 + sl8 * 8]);
      load_lds16(El + ga, &sEl[r * 64 + sl8 * 8]);
    }
    #pragma unroll
    for (int i = 0; i < 4; ++i) {          // C rows 0..63 (32/wave)
      const int r = w * 32 + i * 8 + lrow;
      const size_t gc = (size_t)r * DMODEL + kt + csrc * 8;
      load_lds16(Ch + gc, &sCh[r * 64 + sl8 * 8]);
      load_lds16(Cl + gc, &sCl[r * 64 + sl8 * 8]);
    }
    __syncthreads();
    #pragma unroll
    for (int kk = 0; kk < 2; ++kk) {
      const int sl = ((kk * 4 + (lane >> 4)) ^ (lane & 7)) * 8;
      bf16x8 eh, el, ch[4], cl[4];
      {
        int off = (w * 16 + (lane & 15)) * 64 + sl;
        eh = *(const bf16x8*)&sEh[off];
        el = *(const bf16x8*)&sEl[off];
      }
      #pragma unroll
      for (int ni = 0; ni < 4; ++ni) {
        int off = (ni * 16 + (lane & 15)) * 64 + sl;
        ch[ni] = *(const bf16x8*)&sCh[off];
        cl[ni] = *(const bf16x8*)&sCl[off];
      }
      #pragma unroll
      for (int ni = 0; ni < 4; ++ni) {
        acc[ni] = __builtin_amdgcn_mfma_f32_16x16x32_bf16(eh, ch[ni], acc[ni], 0, 0, 0);
        acc[ni] = __builtin_amdgcn_mfma_f32_16x16x32_bf16(eh, cl[ni], acc[ni], 0, 0, 0);
        acc[ni] = __builtin_amdgcn_mfma_f32_16x16x32_bf16(el, ch[ni], acc[ni], 0, 0, 0);
      }
    }
  }
  #pragma unroll
  for (int ni = 0; ni < 4; ++ni) {
    const int p = w * 16 + (lane >> 4) * 4;
    const int k = ni * 16 + (lane & 15);
    const float csq = csq_l[k];
    #pragma unroll
    for (int r = 0; r < 4; ++r)
      Dmat[p + r][k] = csq - 2.f * acc[ni][r];
  }
  __syncthreads();
  if (t < 32) {
    float best = Dmat[t][0]; int bi = 0;
    #pragma unroll 8
    for (int k = 1; k < KC; ++k) {
      float v = Dmat[t][k];
      if (v < best) { best = v; bi = k; }
    }
    ids[p0 + t] = bi;
    atomicAdd(&cnt_l[bi], 1);
  }
  __syncthreads();
  if (t < 64) pcnt[blockIdx.x * KC + t] = (float)cnt_l[t];
}

// ---------------------------------------------------------------------------
// k2 segsum: psum[g][k][d] = sum_p onehot[k][p] * emb[p][d] via bf16 MFMA.
// grid (4 d-quarters, 64 p-groups of 128), block 256.  [R2 verbatim]
// ---------------------------------------------------------------------------
__global__ __launch_bounds__(256) void k2_segsum(
    const unsigned short* __restrict__ Eth, const unsigned short* __restrict__ Etl,
    const int* __restrict__ ids, const int* __restrict__ done,
    float* __restrict__ psum) {
  if (*done) return;
  __shared__ unsigned short sOH[64 * 136] __attribute__((aligned(16)));
  __shared__ unsigned short sTh[128 * 64] __attribute__((aligned(16)));
  __shared__ unsigned short sTl[128 * 64] __attribute__((aligned(16)));
  __shared__ int ids_l[128];
  const int t = threadIdx.x;
  const int w = t >> 6, lane = t & 63;
  const int dq = blockIdx.x, g = blockIdx.y;
  const int lrow = lane >> 3, sl8 = lane & 7;
  const int csrc = sl8 ^ lrow;

  if (t < 128) ids_l[t] = ids[g * 128 + t];
  __syncthreads();
  #pragma unroll
  for (int q = 0; q < 4; ++q) {
    int c = t * 4 + q;                  // 1024 chunks: 64 cl x 16 p-chunks
    int cl = c >> 4, pc = c & 15;
    unsigned short v[8];
    #pragma unroll
    for (int j = 0; j < 8; ++j)
      v[j] = (ids_l[pc * 8 + j] == cl) ? (unsigned short)0x3F80 : (unsigned short)0;
    *(uint4*)&sOH[cl * 136 + pc * 8] = *(uint4*)&v[0];
  }

  f32x4 acc[4][2];
  #pragma unroll
  for (int i = 0; i < 4; ++i)
    #pragma unroll
    for (int j = 0; j < 2; ++j) acc[i][j] = (f32x4){0.f, 0.f, 0.f, 0.f};

  for (int kt = 0; kt < 2; ++kt) {      // two 64-point K-tiles
    __syncthreads();
    #pragma unroll
    for (int i = 0; i < 4; ++i) {
      const int rr = w * 32 + i * 8 + lrow;   // d-row 0..127
      const size_t gt = (size_t)(dq * 128 + rr) * NPT + g * 128 + kt * 64 + csrc * 8;
      load_lds16(Eth + gt, &sTh[rr * 64 + sl8 * 8]);
      load_lds16(Etl + gt, &sTl[rr * 64 + sl8 * 8]);
    }
    __syncthreads();
    #pragma unroll
    for (int kk = 0; kk < 2; ++kk) {
      const int quad = lane >> 4;
      const int poff = kt * 64 + kk * 32 + quad * 8;
      bf16x8 a[4], bh[2], bl[2];
      #pragma unroll
      for (int mi = 0; mi < 4; ++mi)
        a[mi] = *(const bf16x8*)&sOH[(mi * 16 + (lane & 15)) * 136 + poff];
      const int sl = ((kk * 4 + quad) ^ (lane & 7)) * 8;
      #pragma unroll
      for (int ni = 0; ni < 2; ++ni) {
        int off = (w * 32 + ni * 16 + (lane & 15)) * 64 + sl;
        bh[ni] = *(const bf16x8*)&sTh[off];
        bl[ni] = *(const bf16x8*)&sTl[off];
      }
      #pragma unroll
      for (int mi = 0; mi < 4; ++mi)
        #pragma unroll
        for (int ni = 0; ni < 2; ++ni) {
          acc[mi][ni] = __builtin_amdgcn_mfma_f32_16x16x32_bf16(a[mi], bh[ni], acc[mi][ni], 0, 0, 0);
          acc[mi][ni] = __builtin_amdgcn_mfma_f32_16x16x32_bf16(a[mi], bl[ni], acc[mi][ni], 0, 0, 0);
        }
    }
  }
  #pragma unroll
  for (int mi = 0; mi < 4; ++mi)
    #pragma unroll
    for (int ni = 0; ni < 2; ++ni) {
      const int cl = mi * 16 + (lane >> 4) * 4;
      const int d = dq * 128 + w * 32 + ni * 16 + (lane & 15);
      #pragma unroll
      for (int r = 0; r < 4; ++r)
        psum[((size_t)g * KC + cl + r) * DMODEL + d] = acc[mi][ni][r];
    }
}

// ---------------------------------------------------------------------------
// k3 update: reduce psum (fixed order, unroll-16), new cent (+hi/lo), shift,
// done, per-quarter csq4.  On is_last: also emit one-hot prob + cent copy
// (handles early-convergence via done flag).  grid 256, block 128.
// ---------------------------------------------------------------------------
__global__ __launch_bounds__(128) void k3_update(float* __restrict__ cent,
    unsigned short* __restrict__ centh, unsigned short* __restrict__ centl,
    const float* __restrict__ psum, const float* __restrict__ pcnt,
    int* __restrict__ done, float* __restrict__ csq4,
    float* __restrict__ shift2, int* __restrict__ ticket, int iter,
    const int* __restrict__ ids, float* __restrict__ out, int is_last) {
  const int dn = *done;
  const int bk = blockIdx.x & 63, dq = blockIdx.x >> 6;
  const int t = threadIdx.x;
  const int d = dq * 128 + t;
  __shared__ float red[128];
  __shared__ float cnt_s;
  float outv = 0.f;
  if (!dn) {
    red[t] = pcnt[(size_t)(2 * t) * KC + bk] + pcnt[(size_t)(2 * t + 1) * KC + bk];
    __syncthreads();
    for (int s = 64; s > 0; s >>= 1) { if (t < s) red[t] += red[t + s]; __syncthreads(); }
    if (t == 0) cnt_s = red[0];
    __syncthreads();
    const float count = cnt_s;
    float s = 0.f;
    #pragma unroll 16
    for (int g = 0; g < 64; ++g)
      s += psum[((size_t)g * KC + bk) * DMODEL + d];
    float oldv = cent[bk * DMODEL + d];
    float newv = (count > 0.f) ? (s / fmaxf(count, 1.f)) : oldv;
    cent[bk * DMODEL + d] = newv;
    unsigned short h = bf16_rn(newv);
    centh[bk * DMODEL + d] = h;
    centl[bk * DMODEL + d] = bf16_rn(newv - __uint_as_float((unsigned)h << 16));
    outv = newv;
    float df = newv - oldv;
    red[t] = df * df; __syncthreads();
    for (int s2 = 64; s2 > 0; s2 >>= 1) { if (t < s2) red[t] += red[t + s2]; __syncthreads(); }
    float tot_sh = red[0]; __syncthreads();
    red[t] = newv * newv; __syncthreads();
    for (int s2 = 64; s2 > 0; s2 >>= 1) { if (t < s2) red[t] += red[t + s2]; __syncthreads(); }
    if (t == 0) {
      csq4[dq * KC + bk] = red[0];
      atomicAdd(shift2 + iter, tot_sh);
      __threadfence();
      int tk = atomicAdd(ticket + iter, 1);
      if (tk == 255) {
        float tot = atomicAdd(shift2 + iter, 0.f);
        if (sqrtf(tot) < 1e-4f) *done = 1;
      }
    }
  } else {
    outv = cent[bk * DMODEL + d];
  }
  if (is_last) {
    // centroid copy (this block's (bk, dq) slice)
    out[(size_t)NPT * KC + bk * DMODEL + d] = outv;
    // one-hot for points [bid*32, bid*32+32): thread t -> point bid*32+(t>>2),
    // k-chunk (t&3)*16.
    const int n = blockIdx.x * 32 + (t >> 2);
    const int k0 = (t & 3) * 16;
    const int idn = ids[n];
    #pragma unroll
    for (int j = 0; j < 4; ++j) {
      float4 v;
      v.x = (idn == k0 + j * 4 + 0) ? 1.f : 0.f;
      v.y = (idn == k0 + j * 4 + 1) ? 1.f : 0.f;
      v.z = (idn == k0 + j * 4 + 2) ? 1.f : 0.f;
      v.w = (idn == k0 + j * 4 + 3) ? 1.f : 0.f;
      *(float4*)(out + (size_t)n * KC + k0 + j * 4) = v;
    }
  }
}

// ---------------------------------------------------------------------------
extern "C" void kernel_launch(void* const* d_in, const int* in_sizes, int n_in,
                              void* d_out, int out_size, void* d_ws, size_t ws_size,
                              hipStream_t stream) {
  const float* x    = (const float*)d_in[0];
  const float* W    = (const float*)d_in[1];
  const float* bias = (const float*)d_in[2];
  const float* c0   = (const float*)d_in[3];
  float* out = (float*)d_out;
  float* emb_out = out + NPT * KC + KC * DMODEL;

  char* ws = (char*)d_ws;
  // loop phase (live after gemm finishes):
  unsigned short* Ehi  = (unsigned short*)(ws + 0);
  unsigned short* Elo  = (unsigned short*)(ws + 8388608);
  unsigned short* Eth  = (unsigned short*)(ws + 16777216);
  unsigned short* Etl  = (unsigned short*)(ws + 25165824);
  float* psum    = (float*)(ws + 33554432);
  float* cent    = (float*)(ws + 41943040);
  unsigned short* centh = (unsigned short*)(ws + 42074112);
  unsigned short* centl = (unsigned short*)(ws + 42139648);
  float* csq4    = (float*)(ws + 42205184);   // 4*64 floats
  float* shift2  = (float*)(ws + 42206208);
  int*   ticket  = (int*)(ws + 42206272);
  int*   done_f  = (int*)(ws + 42206336);
  float* pcnt    = (float*)(ws + 42206400);   // 256*64 floats = 64KB
  int*   ids     = (int*)(ws + 42271936);     // 8192 ints
  // gemm phase (aliases loop region; dead before conv_et runs):
  unsigned short* Xh = (unsigned short*)(ws + 0);
  unsigned short* Xl = (unsigned short*)(ws + 33554432);
  unsigned short* Wh = (unsigned short*)(ws + 67108864);
  unsigned short* Wl = (unsigned short*)(ws + 69206016);
  const size_t need_fast = 71303168;
  (void)n_in; (void)in_sizes; (void)out_size;

  if (ws_size >= need_fast) {
    prep_k<<<4096, 256, 0, stream>>>(x, Xh, Xl, W, Wh, Wl);
    gemm_mfma<<<dim3(256, 2), 256, 0, stream>>>(Xh, Xl, Wh, Wl, bias, emb_out);
  } else {
    gemm_emb<<<dim3(4, BSZ), 256, 0, stream>>>(x, W, bias, emb_out);
  }
  conv_et<<<dim3(8, 128), 256, 0, stream>>>(emb_out, Ehi, Elo, Eth, Etl,
                                            c0, cent, centh, centl, csq4,
                                            done_f, shift2, ticket);
  for (int it = 0; it < MAXIT; ++it) {
    k1_assign<<<256, 128, 0, stream>>>(Ehi, Elo, centh, centl, csq4, done_f, ids, pcnt);
    k2_segsum<<<dim3(4, 64), 256, 0, stream>>>(Eth, Etl, ids, done_f, psum);
    k3_update<<<256, 128, 0, stream>>>(cent, centh, centl, psum, pcnt, done_f,
                                       csq4, shift2, ticket, it,
                                       ids, out, it == MAXIT - 1);
  }
}

// Round 8
// 451.635 us; speedup vs baseline: 2.8321x; 1.0691x over previous
//
#include <hip/hip_runtime.h>

#define SEQ 2048
#define NVAR 64
#define DMODEL 512
#define BSZ 128
#define KC 64
#define NPT (BSZ*NVAR)   /* 8192 points */
#define MAXIT 10

typedef __bf16 bf16x8 __attribute__((ext_vector_type(8)));
typedef float f32x4 __attribute__((ext_vector_type(4)));

__device__ __forceinline__ void load_lds16(const void* g, void* l) {
  __builtin_amdgcn_global_load_lds((const __attribute__((address_space(1))) void*)g,
                                   (__attribute__((address_space(3))) void*)l, 16, 0, 0);
}

__device__ __forceinline__ unsigned short bf16_rn(float x) {
  unsigned int u = __float_as_uint(x);
  u += 0x7fffu + ((u >> 16) & 1u);
  return (unsigned short)(u >> 16);
}

// ---------------------------------------------------------------------------
// prep_k: conv_x (all 4096 blocks) + conv_w (blocks 0..1023).
// ---------------------------------------------------------------------------
__global__ __launch_bounds__(256) void prep_k(const float* __restrict__ x,
    unsigned short* __restrict__ Xh, unsigned short* __restrict__ Xl,
    const float* __restrict__ W, unsigned short* __restrict__ Wh,
    unsigned short* __restrict__ Wl) {
  __shared__ float tile[64 * 65];
  const int fid = blockIdx.x;
  const int t = threadIdx.x;

  if (fid < 1024) {
    int i = (fid * 256 + t) * 4;
    float4 v = *(const float4*)(W + i);
    ushort4 h, l;
    h.x = bf16_rn(v.x); l.x = bf16_rn(v.x - __uint_as_float((unsigned)h.x << 16));
    h.y = bf16_rn(v.y); l.y = bf16_rn(v.y - __uint_as_float((unsigned)h.y << 16));
    h.z = bf16_rn(v.z); l.z = bf16_rn(v.z - __uint_as_float((unsigned)h.z << 16));
    h.w = bf16_rn(v.w); l.w = bf16_rn(v.w - __uint_as_float((unsigned)h.w << 16));
    *(ushort4*)(Wh + i) = h;
    *(ushort4*)(Wl + i) = l;
  }

  const int k0 = (fid & 31) * 64;
  const int bs = fid >> 5;
  const float* xb = x + (size_t)bs * SEQ * NVAR + (size_t)k0 * NVAR;
  #pragma unroll
  for (int p = 0; p < 4; ++p) {
    int idx = t + 256 * p;
    int row = idx >> 4, c4 = (idx & 15) * 4;
    float4 v = *(const float4*)(xb + row * NVAR + c4);
    tile[row * 65 + c4 + 0] = v.x; tile[row * 65 + c4 + 1] = v.y;
    tile[row * 65 + c4 + 2] = v.z; tile[row * 65 + c4 + 3] = v.w;
  }
  __syncthreads();
  const int v = t >> 2;
  const int kc = (t & 3) * 16;
  unsigned short h[16], l[16];
  #pragma unroll
  for (int j = 0; j < 16; ++j) {
    float f = tile[(kc + j) * 65 + v];
    h[j] = bf16_rn(f);
    l[j] = bf16_rn(f - __uint_as_float((unsigned)h[j] << 16));
  }
  size_t off = (size_t)(bs * 64 + v) * SEQ + k0 + kc;
  *(uint4*)(Xh + off)     = *(uint4*)&h[0];
  *(uint4*)(Xh + off + 8) = *(uint4*)&h[8];
  *(uint4*)(Xl + off)     = *(uint4*)&l[0];
  *(uint4*)(Xl + off + 8) = *(uint4*)&l[8];
}

// ---------------------------------------------------------------------------
// gemm_mfma: emb = Xt·W^T + b, bf16x3 split.  Tile 64m x 128n, BK=64.
// grid (128 m, 4 n), 256 thr (4 waves: wr=w>>1 (32m), wc=w&1 (64n)).
// LDS 48KB -> up to 3 blocks/CU; 512 blocks = 2/CU resident.
// Same K/3-term order as previous rounds -> emb bitwise identical.
// ---------------------------------------------------------------------------
__global__ __launch_bounds__(256) void gemm_mfma(
    const unsigned short* __restrict__ Ah, const unsigned short* __restrict__ Al,
    const unsigned short* __restrict__ Bh, const unsigned short* __restrict__ Bl,
    const float* __restrict__ bias, float* __restrict__ emb) {
  __shared__ unsigned short sAh[64 * 64] __attribute__((aligned(16)));
  __shared__ unsigned short sAl[64 * 64] __attribute__((aligned(16)));
  __shared__ unsigned short sBh[128 * 64] __attribute__((aligned(16)));
  __shared__ unsigned short sBl[128 * 64] __attribute__((aligned(16)));
  const int t = threadIdx.x;
  const int w = t >> 6, lane = t & 63;
  const int m0 = blockIdx.x * 64;
  const int n0 = blockIdx.y * 128;
  const int wr = w >> 1, wc = w & 1;
  const int lrow = lane >> 3, sl8 = lane & 7;
  const int csrc = sl8 ^ lrow;

  f32x4 acc[2][4];
  #pragma unroll
  for (int i = 0; i < 2; ++i)
    #pragma unroll
    for (int j = 0; j < 4; ++j) acc[i][j] = (f32x4){0.f, 0.f, 0.f, 0.f};

  for (int kt = 0; kt < SEQ; kt += 64) {
    __syncthreads();
    #pragma unroll
    for (int i = 0; i < 2; ++i) {
      const int r = w * 16 + i * 8 + lrow;   // A rows 0..63
      const size_t ga = (size_t)(m0 + r) * SEQ + kt + csrc * 8;
      load_lds16(Ah + ga, &sAh[r * 64 + sl8 * 8]);
      load_lds16(Al + ga, &sAl[r * 64 + sl8 * 8]);
    }
    #pragma unroll
    for (int i = 0; i < 4; ++i) {
      const int r = w * 32 + i * 8 + lrow;   // B rows 0..127
      const size_t gb = (size_t)(n0 + r) * SEQ + kt + csrc * 8;
      load_lds16(Bh + gb, &sBh[r * 64 + sl8 * 8]);
      load_lds16(Bl + gb, &sBl[r * 64 + sl8 * 8]);
    }
    __syncthreads();
    #pragma unroll
    for (int kk = 0; kk < 2; ++kk) {
      const int sl = ((kk * 4 + (lane >> 4)) ^ (lane & 7)) * 8;
      bf16x8 ah[2], al[2], bh[4], bl[4];
      #pragma unroll
      for (int mi = 0; mi < 2; ++mi) {
        int off = (wr * 32 + mi * 16 + (lane & 15)) * 64 + sl;
        ah[mi] = *(const bf16x8*)&sAh[off];
        al[mi] = *(const bf16x8*)&sAl[off];
      }
      #pragma unroll
      for (int ni = 0; ni < 4; ++ni) {
        int off = (wc * 64 + ni * 16 + (lane & 15)) * 64 + sl;
        bh[ni] = *(const bf16x8*)&sBh[off];
        bl[ni] = *(const bf16x8*)&sBl[off];
      }
      #pragma unroll
      for (int mi = 0; mi < 2; ++mi)
        #pragma unroll
        for (int ni = 0; ni < 4; ++ni) {
          acc[mi][ni] = __builtin_amdgcn_mfma_f32_16x16x32_bf16(ah[mi], bh[ni], acc[mi][ni], 0, 0, 0);
          acc[mi][ni] = __builtin_amdgcn_mfma_f32_16x16x32_bf16(ah[mi], bl[ni], acc[mi][ni], 0, 0, 0);
          acc[mi][ni] = __builtin_amdgcn_mfma_f32_16x16x32_bf16(al[mi], bh[ni], acc[mi][ni], 0, 0, 0);
        }
    }
  }
  #pragma unroll
  for (int ni = 0; ni < 4; ++ni) {
    const int n = n0 + wc * 64 + ni * 16 + (lane & 15);
    const float bv = bias[n];
    #pragma unroll
    for (int mi = 0; mi < 2; ++mi) {
      const int m = m0 + wr * 32 + mi * 16 + (lane >> 4) * 4;
      #pragma unroll
      for (int r = 0; r < 4; ++r)
        emb[(size_t)(m + r) * DMODEL + n] = acc[mi][ni][r] + bv;
    }
  }
}

// ---------------------------------------------------------------------------
// gemm_emb: fp32 fallback (only if ws too small).
// ---------------------------------------------------------------------------
__global__ __launch_bounds__(256) void gemm_emb(const float* __restrict__ x,
    const float* __restrict__ W, const float* __restrict__ bias,
    float* __restrict__ emb) {
  __shared__ float As[64][64];
  __shared__ float Ws[64][132];
  const int bs = blockIdx.y;
  const int n0 = blockIdx.x * 128;
  const int t = threadIdx.x;
  const int tx = t & 15, ty = t >> 4;
  float bv[8];
  #pragma unroll
  for (int j = 0; j < 8; ++j) bv[j] = bias[n0 + 8 * tx + j];
  float acc[4][8];
  #pragma unroll
  for (int i = 0; i < 4; ++i)
    #pragma unroll
    for (int j = 0; j < 8; ++j) acc[i][j] = 0.f;
  const float* xb = x + (size_t)bs * SEQ * NVAR;
  for (int k0 = 0; k0 < SEQ; k0 += 64) {
    __syncthreads();
    {
      const float4* src = (const float4*)(xb + (size_t)k0 * NVAR);
      float4* dst = (float4*)&As[0][0];
      #pragma unroll
      for (int r = 0; r < 4; ++r) dst[t + 256 * r] = src[t + 256 * r];
    }
    #pragma unroll
    for (int r = 0; r < 8; ++r) {
      int idx = t + 256 * r;
      int k4 = idx & 15, n = idx >> 4;
      float4 wv = *(const float4*)(W + (size_t)(n0 + n) * SEQ + k0 + 4 * k4);
      Ws[4 * k4 + 0][n] = wv.x; Ws[4 * k4 + 1][n] = wv.y;
      Ws[4 * k4 + 2][n] = wv.z; Ws[4 * k4 + 3][n] = wv.w;
    }
    __syncthreads();
    #pragma unroll 8
    for (int kk = 0; kk < 64; ++kk) {
      const float4 a  = *(const float4*)&As[kk][4 * ty];
      const float4 w0 = *(const float4*)&Ws[kk][8 * tx];
      const float4 w1 = *(const float4*)&Ws[kk][8 * tx + 4];
      const float av[4] = {a.x, a.y, a.z, a.w};
      const float wv[8] = {w0.x, w0.y, w0.z, w0.w, w1.x, w1.y, w1.z, w1.w};
      #pragma unroll
      for (int i = 0; i < 4; ++i)
        #pragma unroll
        for (int j = 0; j < 8; ++j)
          acc[i][j] = fmaf(av[i], wv[j], acc[i][j]);
    }
  }
  #pragma unroll
  for (int i = 0; i < 4; ++i) {
    int row = bs * NVAR + 4 * ty + i;
    float4 o0 = make_float4(acc[i][0] + bv[0], acc[i][1] + bv[1],
                            acc[i][2] + bv[2], acc[i][3] + bv[3]);
    float4 o1 = make_float4(acc[i][4] + bv[4], acc[i][5] + bv[5],
                            acc[i][6] + bv[6], acc[i][7] + bv[7]);
    *(float4*)(emb + (size_t)row * DMODEL + n0 + 8 * tx) = o0;
    *(float4*)(emb + (size_t)row * DMODEL + n0 + 8 * tx + 4) = o1;
  }
}

// ---------------------------------------------------------------------------
// conv_et: emb fp32 -> Ehi/Elo [p][d] AND Eth/Etl [d][p] (LDS transpose),
// PLUS init role (flat block id < 64).
// grid (8 d-tiles, 128 p-tiles) x 256.
// ---------------------------------------------------------------------------
__global__ __launch_bounds__(256) void conv_et(const float* __restrict__ emb,
    unsigned short* __restrict__ Eh, unsigned short* __restrict__ El,
    unsigned short* __restrict__ Eth, unsigned short* __restrict__ Etl,
    const float* __restrict__ c0, float* __restrict__ cent,
    unsigned short* __restrict__ centh, unsigned short* __restrict__ centl,
    float* __restrict__ csq4, int* __restrict__ done,
    float* __restrict__ shift2, int* __restrict__ ticket) {
  __shared__ unsigned short Lh[64][72];
  __shared__ unsigned short Ll[64][72];
  __shared__ float red[256];
  const int d0 = blockIdx.x * 64;
  const int p0 = blockIdx.y * 64;
  const int t = threadIdx.x;
  #pragma unroll
  for (int q = 0; q < 2; ++q) {
    int idx = t + 256 * q;
    int r = idx >> 3, c = idx & 7;
    const float* src = emb + (size_t)(p0 + r) * DMODEL + d0 + c * 8;
    float4 v0 = *(const float4*)src;
    float4 v1 = *(const float4*)(src + 4);
    unsigned short h[8], l[8];
    const float vv[8] = {v0.x, v0.y, v0.z, v0.w, v1.x, v1.y, v1.z, v1.w};
    #pragma unroll
    for (int j = 0; j < 8; ++j) {
      h[j] = bf16_rn(vv[j]);
      l[j] = bf16_rn(vv[j] - __uint_as_float((unsigned)h[j] << 16));
    }
    size_t eo = (size_t)(p0 + r) * DMODEL + d0 + c * 8;
    *(uint4*)(Eh + eo) = *(uint4*)&h[0];
    *(uint4*)(El + eo) = *(uint4*)&l[0];
    *(uint4*)&Lh[r][c * 8] = *(uint4*)&h[0];
    *(uint4*)&Ll[r][c * 8] = *(uint4*)&l[0];
  }
  __syncthreads();
  #pragma unroll
  for (int q = 0; q < 2; ++q) {
    int idx = t + 256 * q;
    int dd = idx >> 3, pc = idx & 7;
    unsigned short h[8], l[8];
    #pragma unroll
    for (int j = 0; j < 8; ++j) {
      h[j] = Lh[pc * 8 + j][dd];
      l[j] = Ll[pc * 8 + j][dd];
    }
    size_t to = (size_t)(d0 + dd) * NPT + p0 + pc * 8;
    *(uint4*)(Eth + to) = *(uint4*)&h[0];
    *(uint4*)(Etl + to) = *(uint4*)&l[0];
  }

  const int fid = blockIdx.x + 8 * blockIdx.y;
  if (fid < KC) {
    const int k = fid;
    float v0, v1;
    {
      int d = t;
      v0 = c0[k * DMODEL + d];
      cent[k * DMODEL + d] = v0;
      unsigned short h = bf16_rn(v0);
      centh[k * DMODEL + d] = h;
      centl[k * DMODEL + d] = bf16_rn(v0 - __uint_as_float((unsigned)h << 16));
    }
    {
      int d = t + 256;
      v1 = c0[k * DMODEL + d];
      cent[k * DMODEL + d] = v1;
      unsigned short h = bf16_rn(v1);
      centh[k * DMODEL + d] = h;
      centl[k * DMODEL + d] = bf16_rn(v1 - __uint_as_float((unsigned)h << 16));
    }
    __syncthreads();
    red[t] = v0 * v0; __syncthreads();
    for (int s = 64; s > 0; s >>= 1) { if ((t & 127) < s) red[t] += red[t + s]; __syncthreads(); }
    if (t == 0)   csq4[0 * KC + k] = red[0];
    if (t == 128) csq4[1 * KC + k] = red[128];
    __syncthreads();
    red[t] = v1 * v1; __syncthreads();
    for (int s = 64; s > 0; s >>= 1) { if ((t & 127) < s) red[t] += red[t + s]; __syncthreads(); }
    if (t == 0)   csq4[2 * KC + k] = red[0];
    if (t == 128) csq4[3 * KC + k] = red[128];
    if (k == 0 && t < MAXIT) { shift2[t] = 0.f; ticket[t] = 0; }
    if (k == 0 && t == 31) *done = 0;
  }
}

// ---------------------------------------------------------------------------
// k1 assign: BK=128 (two stacked 64-wide sub-tiles, original linear staging
// per sub-tile) -> 4 staging rounds instead of 8.  K order preserved ->
// bitwise-identical accumulation.  grid 256 (32 p), block 128 (2 waves).
// ---------------------------------------------------------------------------
__global__ __launch_bounds__(128) void k1_assign(
    const unsigned short* __restrict__ Eh, const unsigned short* __restrict__ El,
    const unsigned short* __restrict__ Ch, const unsigned short* __restrict__ Cl,
    const float* __restrict__ csq4, const int* __restrict__ done,
    int* __restrict__ ids, float* __restrict__ pcnt) {
  if (*done) return;
  __shared__ unsigned short sEh[2][32 * 64] __attribute__((aligned(16)));
  __shared__ unsigned short sEl[2][32 * 64] __attribute__((aligned(16)));
  __shared__ unsigned short sCh[2][64 * 64] __attribute__((aligned(16)));
  __shared__ unsigned short sCl[2][64 * 64] __attribute__((aligned(16)));
  __shared__ float Dmat[32][65];
  __shared__ float csq_l[64];
  __shared__ int cnt_l[64];
  const int t = threadIdx.x;
  const int w = t >> 6, lane = t & 63;
  const int p0 = blockIdx.x * 32;
  const int lrow = lane >> 3, sl8 = lane & 7;
  const int csrc = sl8 ^ lrow;
  if (t < 64) {
    csq_l[t] = csq4[t] + csq4[KC + t] + csq4[2 * KC + t] + csq4[3 * KC + t];
    cnt_l[t] = 0;
  }

  f32x4 acc[4];
  #pragma unroll
  for (int j = 0; j < 4; ++j) acc[j] = (f32x4){0.f, 0.f, 0.f, 0.f};

  for (int kt = 0; kt < DMODEL; kt += 128) {
    __syncthreads();
    #pragma unroll
    for (int h = 0; h < 2; ++h) {
      #pragma unroll
      for (int i = 0; i < 2; ++i) {          // E rows 0..31 (16/wave)
        const int r = w * 16 + i * 8 + lrow;
        const size_t ga = (size_t)(p0 + r) * DMODEL + kt + h * 64 + csrc * 8;
        load_lds16(Eh + ga, &sEh[h][r * 64 + sl8 * 8]);
        load_lds16(El + ga, &sEl[h][r * 64 + sl8 * 8]);
      }
      #pragma unroll
      for (int i = 0; i < 4; ++i) {          // C rows 0..63 (32/wave)
        const int r = w * 32 + i * 8 + lrow;
        const size_t gc = (size_t)r * DMODEL + kt + h * 64 + csrc * 8;
        load_lds16(Ch + gc, &sCh[h][r * 64 + sl8 * 8]);
        load_lds16(Cl + gc, &sCl[h][r * 64 + sl8 * 8]);
      }
    }
    __syncthreads();
    #pragma unroll
    for (int kk4 = 0; kk4 < 4; ++kk4) {      // K: 0-31,32-63,64-95,96-127
      const int h = kk4 >> 1, kk2 = kk4 & 1;
      const int sl = ((kk2 * 4 + (lane >> 4)) ^ (lane & 7)) * 8;
      bf16x8 eh, el, ch[4], cl[4];
      {
        int off = (w * 16 + (lane & 15)) * 64 + sl;
        eh = *(const bf16x8*)&sEh[h][off];
        el = *(const bf16x8*)&sEl[h][off];
      }
      #pragma unroll
      for (int ni = 0; ni < 4; ++ni) {
        int off = (ni * 16 + (lane & 15)) * 64 + sl;
        ch[ni] = *(const bf16x8*)&sCh[h][off];
        cl[ni] = *(const bf16x8*)&sCl[h][off];
      }
      #pragma unroll
      for (int ni = 0; ni < 4; ++ni) {
        acc[ni] = __builtin_amdgcn_mfma_f32_16x16x32_bf16(eh, ch[ni], acc[ni], 0, 0, 0);
        acc[ni] = __builtin_amdgcn_mfma_f32_16x16x32_bf16(eh, cl[ni], acc[ni], 0, 0, 0);
        acc[ni] = __builtin_amdgcn_mfma_f32_16x16x32_bf16(el, ch[ni], acc[ni], 0, 0, 0);
      }
    }
  }
  #pragma unroll
  for (int ni = 0; ni < 4; ++ni) {
    const int p = w * 16 + (lane >> 4) * 4;
    const int k = ni * 16 + (lane & 15);
    const float csq = csq_l[k];
    #pragma unroll
    for (int r = 0; r < 4; ++r)
      Dmat[p + r][k] = csq - 2.f * acc[ni][r];
  }
  __syncthreads();
  if (t < 32) {
    float best = Dmat[t][0]; int bi = 0;
    #pragma unroll 8
    for (int k = 1; k < KC; ++k) {
      float v = Dmat[t][k];
      if (v < best) { best = v; bi = k; }
    }
    ids[p0 + t] = bi;
    atomicAdd(&cnt_l[bi], 1);
  }
  __syncthreads();
  if (t < 64) pcnt[blockIdx.x * KC + t] = (float)cnt_l[t];
}

// ---------------------------------------------------------------------------
// k2 segsum: single 128-point pass (both 64-halves staged at once).
// K order: kk4*32 == old kt*64+kk*32 -> bitwise identical.
// grid (4 dq, 64 g), block 256 (4 waves).
// ---------------------------------------------------------------------------
__global__ __launch_bounds__(256) void k2_segsum(
    const unsigned short* __restrict__ Eth, const unsigned short* __restrict__ Etl,
    const int* __restrict__ ids, const int* __restrict__ done,
    float* __restrict__ psum) {
  if (*done) return;
  __shared__ unsigned short sOH[64 * 136] __attribute__((aligned(16)));
  __shared__ unsigned short sTh[2][128 * 64] __attribute__((aligned(16)));
  __shared__ unsigned short sTl[2][128 * 64] __attribute__((aligned(16)));
  __shared__ int ids_l[128];
  const int t = threadIdx.x;
  const int w = t >> 6, lane = t & 63;
  const int dq = blockIdx.x, g = blockIdx.y;
  const int lrow = lane >> 3, sl8 = lane & 7;
  const int csrc = sl8 ^ lrow;

  if (t < 128) ids_l[t] = ids[g * 128 + t];
  __syncthreads();
  // stage both 64-point halves
  #pragma unroll
  for (int h = 0; h < 2; ++h) {
    #pragma unroll
    for (int i = 0; i < 4; ++i) {
      const int rr = w * 32 + i * 8 + lrow;   // d-row 0..127
      const size_t gt = (size_t)(dq * 128 + rr) * NPT + g * 128 + h * 64 + csrc * 8;
      load_lds16(Eth + gt, &sTh[h][rr * 64 + sl8 * 8]);
      load_lds16(Etl + gt, &sTl[h][rr * 64 + sl8 * 8]);
    }
  }
  // one-hot build (LDS writes; drained by the same barrier)
  #pragma unroll
  for (int q = 0; q < 4; ++q) {
    int c = t * 4 + q;                  // 1024 chunks: 64 cl x 16 p-chunks
    int cl = c >> 4, pc = c & 15;
    unsigned short v[8];
    #pragma unroll
    for (int j = 0; j < 8; ++j)
      v[j] = (ids_l[pc * 8 + j] == cl) ? (unsigned short)0x3F80 : (unsigned short)0;
    *(uint4*)&sOH[cl * 136 + pc * 8] = *(uint4*)&v[0];
  }

  f32x4 acc[4][2];
  #pragma unroll
  for (int i = 0; i < 4; ++i)
    #pragma unroll
    for (int j = 0; j < 2; ++j) acc[i][j] = (f32x4){0.f, 0.f, 0.f, 0.f};

  __syncthreads();
  #pragma unroll
  for (int kk4 = 0; kk4 < 4; ++kk4) {   // points 0-31,32-63,64-95,96-127
    const int h = kk4 >> 1, kk2 = kk4 & 1;
    const int quad = lane >> 4;
    const int poff = kk4 * 32 + quad * 8;
    bf16x8 a[4], bh[2], bl[2];
    #pragma unroll
    for (int mi = 0; mi < 4; ++mi)
      a[mi] = *(const bf16x8*)&sOH[(mi * 16 + (lane & 15)) * 136 + poff];
    const int sl = ((kk2 * 4 + quad) ^ (lane & 7)) * 8;
    #pragma unroll
    for (int ni = 0; ni < 2; ++ni) {
      int off = (w * 32 + ni * 16 + (lane & 15)) * 64 + sl;
      bh[ni] = *(const bf16x8*)&sTh[h][off];
      bl[ni] = *(const bf16x8*)&sTl[h][off];
    }
    #pragma unroll
    for (int mi = 0; mi < 4; ++mi)
      #pragma unroll
      for (int ni = 0; ni < 2; ++ni) {
        acc[mi][ni] = __builtin_amdgcn_mfma_f32_16x16x32_bf16(a[mi], bh[ni], acc[mi][ni], 0, 0, 0);
        acc[mi][ni] = __builtin_amdgcn_mfma_f32_16x16x32_bf16(a[mi], bl[ni], acc[mi][ni], 0, 0, 0);
      }
  }
  #pragma unroll
  for (int mi = 0; mi < 4; ++mi)
    #pragma unroll
    for (int ni = 0; ni < 2; ++ni) {
      const int cl = mi * 16 + (lane >> 4) * 4;
      const int d = dq * 128 + w * 32 + ni * 16 + (lane & 15);
      #pragma unroll
      for (int r = 0; r < 4; ++r)
        psum[((size_t)g * KC + cl + r) * DMODEL + d] = acc[mi][ni][r];
    }
}

// ---------------------------------------------------------------------------
// k3 update (R7 verbatim): reduce psum, new cent (+hi/lo), shift, done,
// csq4; on is_last also one-hot + cent copy.  grid 256, block 128.
// ---------------------------------------------------------------------------
__global__ __launch_bounds__(128) void k3_update(float* __restrict__ cent,
    unsigned short* __restrict__ centh, unsigned short* __restrict__ centl,
    const float* __restrict__ psum, const float* __restrict__ pcnt,
    int* __restrict__ done, float* __restrict__ csq4,
    float* __restrict__ shift2, int* __restrict__ ticket, int iter,
    const int* __restrict__ ids, float* __restrict__ out, int is_last) {
  const int dn = *done;
  const int bk = blockIdx.x & 63, dq = blockIdx.x >> 6;
  const int t = threadIdx.x;
  const int d = dq * 128 + t;
  __shared__ float red[128];
  __shared__ float cnt_s;
  float outv = 0.f;
  if (!dn) {
    red[t] = pcnt[(size_t)(2 * t) * KC + bk] + pcnt[(size_t)(2 * t + 1) * KC + bk];
    __syncthreads();
    for (int s = 64; s > 0; s >>= 1) { if (t < s) red[t] += red[t + s]; __syncthreads(); }
    if (t == 0) cnt_s = red[0];
    __syncthreads();
    const float count = cnt_s;
    float s = 0.f;
    #pragma unroll 16
    for (int g = 0; g < 64; ++g)
      s += psum[((size_t)g * KC + bk) * DMODEL + d];
    float oldv = cent[bk * DMODEL + d];
    float newv = (count > 0.f) ? (s / fmaxf(count, 1.f)) : oldv;
    cent[bk * DMODEL + d] = newv;
    unsigned short h = bf16_rn(newv);
    centh[bk * DMODEL + d] = h;
    centl[bk * DMODEL + d] = bf16_rn(newv - __uint_as_float((unsigned)h << 16));
    outv = newv;
    float df = newv - oldv;
    red[t] = df * df; __syncthreads();
    for (int s2 = 64; s2 > 0; s2 >>= 1) { if (t < s2) red[t] += red[t + s2]; __syncthreads(); }
    float tot_sh = red[0]; __syncthreads();
    red[t] = newv * newv; __syncthreads();
    for (int s2 = 64; s2 > 0; s2 >>= 1) { if (t < s2) red[t] += red[t + s2]; __syncthreads(); }
    if (t == 0) {
      csq4[dq * KC + bk] = red[0];
      atomicAdd(shift2 + iter, tot_sh);
      __threadfence();
      int tk = atomicAdd(ticket + iter, 1);
      if (tk == 255) {
        float tot = atomicAdd(shift2 + iter, 0.f);
        if (sqrtf(tot) < 1e-4f) *done = 1;
      }
    }
  } else {
    outv = cent[bk * DMODEL + d];
  }
  if (is_last) {
    out[(size_t)NPT * KC + bk * DMODEL + d] = outv;
    const int n = blockIdx.x * 32 + (t >> 2);
    const int k0 = (t & 3) * 16;
    const int idn = ids[n];
    #pragma unroll
    for (int j = 0; j < 4; ++j) {
      float4 v;
      v.x = (idn == k0 + j * 4 + 0) ? 1.f : 0.f;
      v.y = (idn == k0 + j * 4 + 1) ? 1.f : 0.f;
      v.z = (idn == k0 + j * 4 + 2) ? 1.f : 0.f;
      v.w = (idn == k0 + j * 4 + 3) ? 1.f : 0.f;
      *(float4*)(out + (size_t)n * KC + k0 + j * 4) = v;
    }
  }
}

// ---------------------------------------------------------------------------
extern "C" void kernel_launch(void* const* d_in, const int* in_sizes, int n_in,
                              void* d_out, int out_size, void* d_ws, size_t ws_size,
                              hipStream_t stream) {
  const float* x    = (const float*)d_in[0];
  const float* W    = (const float*)d_in[1];
  const float* bias = (const float*)d_in[2];
  const float* c0   = (const float*)d_in[3];
  float* out = (float*)d_out;
  float* emb_out = out + NPT * KC + KC * DMODEL;

  char* ws = (char*)d_ws;
  unsigned short* Ehi  = (unsigned short*)(ws + 0);
  unsigned short* Elo  = (unsigned short*)(ws + 8388608);
  unsigned short* Eth  = (unsigned short*)(ws + 16777216);
  unsigned short* Etl  = (unsigned short*)(ws + 25165824);
  float* psum    = (float*)(ws + 33554432);
  float* cent    = (float*)(ws + 41943040);
  unsigned short* centh = (unsigned short*)(ws + 42074112);
  unsigned short* centl = (unsigned short*)(ws + 42139648);
  float* csq4    = (float*)(ws + 42205184);
  float* shift2  = (float*)(ws + 42206208);
  int*   ticket  = (int*)(ws + 42206272);
  int*   done_f  = (int*)(ws + 42206336);
  float* pcnt    = (float*)(ws + 42206400);
  int*   ids     = (int*)(ws + 42271936);
  unsigned short* Xh = (unsigned short*)(ws + 0);
  unsigned short* Xl = (unsigned short*)(ws + 33554432);
  unsigned short* Wh = (unsigned short*)(ws + 67108864);
  unsigned short* Wl = (unsigned short*)(ws + 69206016);
  const size_t need_fast = 71303168;
  (void)n_in; (void)in_sizes; (void)out_size;

  if (ws_size >= need_fast) {
    prep_k<<<4096, 256, 0, stream>>>(x, Xh, Xl, W, Wh, Wl);
    gemm_mfma<<<dim3(128, 4), 256, 0, stream>>>(Xh, Xl, Wh, Wl, bias, emb_out);
  } else {
    gemm_emb<<<dim3(4, BSZ), 256, 0, stream>>>(x, W, bias, emb_out);
  }
  conv_et<<<dim3(8, 128), 256, 0, stream>>>(emb_out, Ehi, Elo, Eth, Etl,
                                            c0, cent, centh, centl, csq4,
                                            done_f, shift2, ticket);
  for (int it = 0; it < MAXIT; ++it) {
    k1_assign<<<256, 128, 0, stream>>>(Ehi, Elo, centh, centl, csq4, done_f, ids, pcnt);
    k2_segsum<<<dim3(4, 64), 256, 0, stream>>>(Eth, Etl, ids, done_f, psum);
    k3_update<<<256, 128, 0, stream>>>(cent, centh, centl, psum, pcnt, done_f,
                                       csq4, shift2, ticket, it,
                                       ids, out, it == MAXIT - 1);
  }
}

// Round 9
// 435.352 us; speedup vs baseline: 2.9381x; 1.0374x over previous
//
#include <hip/hip_runtime.h>

#define SEQ 2048
#define NVAR 64
#define DMODEL 512
#define BSZ 128
#define KC 64
#define NPT (BSZ*NVAR)   /* 8192 points */
#define MAXIT 10

typedef __bf16 bf16x8 __attribute__((ext_vector_type(8)));
typedef float f32x4 __attribute__((ext_vector_type(4)));

__device__ __forceinline__ void load_lds16(const void* g, void* l) {
  __builtin_amdgcn_global_load_lds((const __attribute__((address_space(1))) void*)g,
                                   (__attribute__((address_space(3))) void*)l, 16, 0, 0);
}

__device__ __forceinline__ unsigned short bf16_rn(float x) {
  unsigned int u = __float_as_uint(x);
  u += 0x7fffu + ((u >> 16) & 1u);
  return (unsigned short)(u >> 16);
}

// ---------------------------------------------------------------------------
// prep_k: conv_x (all 4096 blocks) + conv_w (blocks 0..1023).
// ---------------------------------------------------------------------------
__global__ __launch_bounds__(256) void prep_k(const float* __restrict__ x,
    unsigned short* __restrict__ Xh, unsigned short* __restrict__ Xl,
    const float* __restrict__ W, unsigned short* __restrict__ Wh,
    unsigned short* __restrict__ Wl) {
  __shared__ float tile[64 * 65];
  const int fid = blockIdx.x;
  const int t = threadIdx.x;

  if (fid < 1024) {
    int i = (fid * 256 + t) * 4;
    float4 v = *(const float4*)(W + i);
    ushort4 h, l;
    h.x = bf16_rn(v.x); l.x = bf16_rn(v.x - __uint_as_float((unsigned)h.x << 16));
    h.y = bf16_rn(v.y); l.y = bf16_rn(v.y - __uint_as_float((unsigned)h.y << 16));
    h.z = bf16_rn(v.z); l.z = bf16_rn(v.z - __uint_as_float((unsigned)h.z << 16));
    h.w = bf16_rn(v.w); l.w = bf16_rn(v.w - __uint_as_float((unsigned)h.w << 16));
    *(ushort4*)(Wh + i) = h;
    *(ushort4*)(Wl + i) = l;
  }

  const int k0 = (fid & 31) * 64;
  const int bs = fid >> 5;
  const float* xb = x + (size_t)bs * SEQ * NVAR + (size_t)k0 * NVAR;
  #pragma unroll
  for (int p = 0; p < 4; ++p) {
    int idx = t + 256 * p;
    int row = idx >> 4, c4 = (idx & 15) * 4;
    float4 v = *(const float4*)(xb + row * NVAR + c4);
    tile[row * 65 + c4 + 0] = v.x; tile[row * 65 + c4 + 1] = v.y;
    tile[row * 65 + c4 + 2] = v.z; tile[row * 65 + c4 + 3] = v.w;
  }
  __syncthreads();
  const int v = t >> 2;
  const int kc = (t & 3) * 16;
  unsigned short h[16], l[16];
  #pragma unroll
  for (int j = 0; j < 16; ++j) {
    float f = tile[(kc + j) * 65 + v];
    h[j] = bf16_rn(f);
    l[j] = bf16_rn(f - __uint_as_float((unsigned)h[j] << 16));
  }
  size_t off = (size_t)(bs * 64 + v) * SEQ + k0 + kc;
  *(uint4*)(Xh + off)     = *(uint4*)&h[0];
  *(uint4*)(Xh + off + 8) = *(uint4*)&h[8];
  *(uint4*)(Xl + off)     = *(uint4*)&l[0];
  *(uint4*)(Xl + off + 8) = *(uint4*)&l[8];
}

// ---------------------------------------------------------------------------
// gemm_mfma: emb = Xt·W^T + b, bf16x3 split.  Tile 64m x 128n, BK=64.
// grid (128 m, 4 n), 256 thr (4 waves: wr=w>>1 (32m), wc=w&1 (64n)).
// ---------------------------------------------------------------------------
__global__ __launch_bounds__(256) void gemm_mfma(
    const unsigned short* __restrict__ Ah, const unsigned short* __restrict__ Al,
    const unsigned short* __restrict__ Bh, const unsigned short* __restrict__ Bl,
    const float* __restrict__ bias, float* __restrict__ emb) {
  __shared__ unsigned short sAh[64 * 64] __attribute__((aligned(16)));
  __shared__ unsigned short sAl[64 * 64] __attribute__((aligned(16)));
  __shared__ unsigned short sBh[128 * 64] __attribute__((aligned(16)));
  __shared__ unsigned short sBl[128 * 64] __attribute__((aligned(16)));
  const int t = threadIdx.x;
  const int w = t >> 6, lane = t & 63;
  const int m0 = blockIdx.x * 64;
  const int n0 = blockIdx.y * 128;
  const int wr = w >> 1, wc = w & 1;
  const int lrow = lane >> 3, sl8 = lane & 7;
  const int csrc = sl8 ^ lrow;

  f32x4 acc[2][4];
  #pragma unroll
  for (int i = 0; i < 2; ++i)
    #pragma unroll
    for (int j = 0; j < 4; ++j) acc[i][j] = (f32x4){0.f, 0.f, 0.f, 0.f};

  for (int kt = 0; kt < SEQ; kt += 64) {
    __syncthreads();
    #pragma unroll
    for (int i = 0; i < 2; ++i) {
      const int r = w * 16 + i * 8 + lrow;   // A rows 0..63
      const size_t ga = (size_t)(m0 + r) * SEQ + kt + csrc * 8;
      load_lds16(Ah + ga, &sAh[r * 64 + sl8 * 8]);
      load_lds16(Al + ga, &sAl[r * 64 + sl8 * 8]);
    }
    #pragma unroll
    for (int i = 0; i < 4; ++i) {
      const int r = w * 32 + i * 8 + lrow;   // B rows 0..127
      const size_t gb = (size_t)(n0 + r) * SEQ + kt + csrc * 8;
      load_lds16(Bh + gb, &sBh[r * 64 + sl8 * 8]);
      load_lds16(Bl + gb, &sBl[r * 64 + sl8 * 8]);
    }
    __syncthreads();
    #pragma unroll
    for (int kk = 0; kk < 2; ++kk) {
      const int sl = ((kk * 4 + (lane >> 4)) ^ (lane & 7)) * 8;
      bf16x8 ah[2], al[2], bh[4], bl[4];
      #pragma unroll
      for (int mi = 0; mi < 2; ++mi) {
        int off = (wr * 32 + mi * 16 + (lane & 15)) * 64 + sl;
        ah[mi] = *(const bf16x8*)&sAh[off];
        al[mi] = *(const bf16x8*)&sAl[off];
      }
      #pragma unroll
      for (int ni = 0; ni < 4; ++ni) {
        int off = (wc * 64 + ni * 16 + (lane & 15)) * 64 + sl;
        bh[ni] = *(const bf16x8*)&sBh[off];
        bl[ni] = *(const bf16x8*)&sBl[off];
      }
      #pragma unroll
      for (int mi = 0; mi < 2; ++mi)
        #pragma unroll
        for (int ni = 0; ni < 4; ++ni) {
          acc[mi][ni] = __builtin_amdgcn_mfma_f32_16x16x32_bf16(ah[mi], bh[ni], acc[mi][ni], 0, 0, 0);
          acc[mi][ni] = __builtin_amdgcn_mfma_f32_16x16x32_bf16(ah[mi], bl[ni], acc[mi][ni], 0, 0, 0);
          acc[mi][ni] = __builtin_amdgcn_mfma_f32_16x16x32_bf16(al[mi], bh[ni], acc[mi][ni], 0, 0, 0);
        }
    }
  }
  #pragma unroll
  for (int ni = 0; ni < 4; ++ni) {
    const int n = n0 + wc * 64 + ni * 16 + (lane & 15);
    const float bv = bias[n];
    #pragma unroll
    for (int mi = 0; mi < 2; ++mi) {
      const int m = m0 + wr * 32 + mi * 16 + (lane >> 4) * 4;
      #pragma unroll
      for (int r = 0; r < 4; ++r)
        emb[(size_t)(m + r) * DMODEL + n] = acc[mi][ni][r] + bv;
    }
  }
}

// ---------------------------------------------------------------------------
// gemm_emb: fp32 fallback (only if ws too small).
// ---------------------------------------------------------------------------
__global__ __launch_bounds__(256) void gemm_emb(const float* __restrict__ x,
    const float* __restrict__ W, const float* __restrict__ bias,
    float* __restrict__ emb) {
  __shared__ float As[64][64];
  __shared__ float Ws[64][132];
  const int bs = blockIdx.y;
  const int n0 = blockIdx.x * 128;
  const int t = threadIdx.x;
  const int tx = t & 15, ty = t >> 4;
  float bv[8];
  #pragma unroll
  for (int j = 0; j < 8; ++j) bv[j] = bias[n0 + 8 * tx + j];
  float acc[4][8];
  #pragma unroll
  for (int i = 0; i < 4; ++i)
    #pragma unroll
    for (int j = 0; j < 8; ++j) acc[i][j] = 0.f;
  const float* xb = x + (size_t)bs * SEQ * NVAR;
  for (int k0 = 0; k0 < SEQ; k0 += 64) {
    __syncthreads();
    {
      const float4* src = (const float4*)(xb + (size_t)k0 * NVAR);
      float4* dst = (float4*)&As[0][0];
      #pragma unroll
      for (int r = 0; r < 4; ++r) dst[t + 256 * r] = src[t + 256 * r];
    }
    #pragma unroll
    for (int r = 0; r < 8; ++r) {
      int idx = t + 256 * r;
      int k4 = idx & 15, n = idx >> 4;
      float4 wv = *(const float4*)(W + (size_t)(n0 + n) * SEQ + k0 + 4 * k4);
      Ws[4 * k4 + 0][n] = wv.x; Ws[4 * k4 + 1][n] = wv.y;
      Ws[4 * k4 + 2][n] = wv.z; Ws[4 * k4 + 3][n] = wv.w;
    }
    __syncthreads();
    #pragma unroll 8
    for (int kk = 0; kk < 64; ++kk) {
      const float4 a  = *(const float4*)&As[kk][4 * ty];
      const float4 w0 = *(const float4*)&Ws[kk][8 * tx];
      const float4 w1 = *(const float4*)&Ws[kk][8 * tx + 4];
      const float av[4] = {a.x, a.y, a.z, a.w};
      const float wv[8] = {w0.x, w0.y, w0.z, w0.w, w1.x, w1.y, w1.z, w1.w};
      #pragma unroll
      for (int i = 0; i < 4; ++i)
        #pragma unroll
        for (int j = 0; j < 8; ++j)
          acc[i][j] = fmaf(av[i], wv[j], acc[i][j]);
    }
  }
  #pragma unroll
  for (int i = 0; i < 4; ++i) {
    int row = bs * NVAR + 4 * ty + i;
    float4 o0 = make_float4(acc[i][0] + bv[0], acc[i][1] + bv[1],
                            acc[i][2] + bv[2], acc[i][3] + bv[3]);
    float4 o1 = make_float4(acc[i][4] + bv[4], acc[i][5] + bv[5],
                            acc[i][6] + bv[6], acc[i][7] + bv[7]);
    *(float4*)(emb + (size_t)row * DMODEL + n0 + 8 * tx) = o0;
    *(float4*)(emb + (size_t)row * DMODEL + n0 + 8 * tx + 4) = o1;
  }
}

// ---------------------------------------------------------------------------
// conv_et: emb fp32 -> Ehi/Elo [p][d] AND Eth/Etl [d][p] (LDS transpose),
// PLUS init role (flat block id < 64).
// grid (8 d-tiles, 128 p-tiles) x 256.
// ---------------------------------------------------------------------------
__global__ __launch_bounds__(256) void conv_et(const float* __restrict__ emb,
    unsigned short* __restrict__ Eh, unsigned short* __restrict__ El,
    unsigned short* __restrict__ Eth, unsigned short* __restrict__ Etl,
    const float* __restrict__ c0, float* __restrict__ cent,
    unsigned short* __restrict__ centh, unsigned short* __restrict__ centl,
    float* __restrict__ csq4, int* __restrict__ done,
    float* __restrict__ shift2, int* __restrict__ ticket) {
  __shared__ unsigned short Lh[64][72];
  __shared__ unsigned short Ll[64][72];
  __shared__ float red[256];
  const int d0 = blockIdx.x * 64;
  const int p0 = blockIdx.y * 64;
  const int t = threadIdx.x;
  #pragma unroll
  for (int q = 0; q < 2; ++q) {
    int idx = t + 256 * q;
    int r = idx >> 3, c = idx & 7;
    const float* src = emb + (size_t)(p0 + r) * DMODEL + d0 + c * 8;
    float4 v0 = *(const float4*)src;
    float4 v1 = *(const float4*)(src + 4);
    unsigned short h[8], l[8];
    const float vv[8] = {v0.x, v0.y, v0.z, v0.w, v1.x, v1.y, v1.z, v1.w};
    #pragma unroll
    for (int j = 0; j < 8; ++j) {
      h[j] = bf16_rn(vv[j]);
      l[j] = bf16_rn(vv[j] - __uint_as_float((unsigned)h[j] << 16));
    }
    size_t eo = (size_t)(p0 + r) * DMODEL + d0 + c * 8;
    *(uint4*)(Eh + eo) = *(uint4*)&h[0];
    *(uint4*)(El + eo) = *(uint4*)&l[0];
    *(uint4*)&Lh[r][c * 8] = *(uint4*)&h[0];
    *(uint4*)&Ll[r][c * 8] = *(uint4*)&l[0];
  }
  __syncthreads();
  #pragma unroll
  for (int q = 0; q < 2; ++q) {
    int idx = t + 256 * q;
    int dd = idx >> 3, pc = idx & 7;
    unsigned short h[8], l[8];
    #pragma unroll
    for (int j = 0; j < 8; ++j) {
      h[j] = Lh[pc * 8 + j][dd];
      l[j] = Ll[pc * 8 + j][dd];
    }
    size_t to = (size_t)(d0 + dd) * NPT + p0 + pc * 8;
    *(uint4*)(Eth + to) = *(uint4*)&h[0];
    *(uint4*)(Etl + to) = *(uint4*)&l[0];
  }

  const int fid = blockIdx.x + 8 * blockIdx.y;
  if (fid < KC) {
    const int k = fid;
    float v0, v1;
    {
      int d = t;
      v0 = c0[k * DMODEL + d];
      cent[k * DMODEL + d] = v0;
      unsigned short h = bf16_rn(v0);
      centh[k * DMODEL + d] = h;
      centl[k * DMODEL + d] = bf16_rn(v0 - __uint_as_float((unsigned)h << 16));
    }
    {
      int d = t + 256;
      v1 = c0[k * DMODEL + d];
      cent[k * DMODEL + d] = v1;
      unsigned short h = bf16_rn(v1);
      centh[k * DMODEL + d] = h;
      centl[k * DMODEL + d] = bf16_rn(v1 - __uint_as_float((unsigned)h << 16));
    }
    __syncthreads();
    red[t] = v0 * v0; __syncthreads();
    for (int s = 64; s > 0; s >>= 1) { if ((t & 127) < s) red[t] += red[t + s]; __syncthreads(); }
    if (t == 0)   csq4[0 * KC + k] = red[0];
    if (t == 128) csq4[1 * KC + k] = red[128];
    __syncthreads();
    red[t] = v1 * v1; __syncthreads();
    for (int s = 64; s > 0; s >>= 1) { if ((t & 127) < s) red[t] += red[t + s]; __syncthreads(); }
    if (t == 0)   csq4[2 * KC + k] = red[0];
    if (t == 128) csq4[3 * KC + k] = red[128];
    if (k == 0 && t < MAXIT) { shift2[t] = 0.f; ticket[t] = 0; }
    if (k == 0 && t == 31) *done = 0;
  }
}

// ---------------------------------------------------------------------------
// k1 assign: 16 points/block, 256 thr (4 waves; wave w owns k-quadrant
// [w*16, w*16+16)).  BK=128, 4 staging rounds.  Per-(p,k) K-accumulation
// chain, 3-term order, and argmin scan order unchanged -> bitwise identical.
// grid 512, 2 blocks/CU (44KB LDS) -> 8 waves/CU.
// ---------------------------------------------------------------------------
__global__ __launch_bounds__(256) void k1_assign(
    const unsigned short* __restrict__ Eh, const unsigned short* __restrict__ El,
    const unsigned short* __restrict__ Ch, const unsigned short* __restrict__ Cl,
    const float* __restrict__ csq4, const int* __restrict__ done,
    int* __restrict__ ids, float* __restrict__ pcnt) {
  if (*done) return;
  __shared__ unsigned short sEh[2][16 * 64] __attribute__((aligned(16)));
  __shared__ unsigned short sEl[2][16 * 64] __attribute__((aligned(16)));
  __shared__ unsigned short sCh[2][64 * 64] __attribute__((aligned(16)));
  __shared__ unsigned short sCl[2][64 * 64] __attribute__((aligned(16)));
  __shared__ float Dmat[16][65];
  __shared__ float csq_l[64];
  __shared__ int cnt_l[64];
  const int t = threadIdx.x;
  const int w = t >> 6, lane = t & 63;
  const int p0 = blockIdx.x * 16;
  const int lrow = lane >> 3, sl8 = lane & 7;
  const int csrc = sl8 ^ lrow;
  if (t < 64) {
    csq_l[t] = csq4[t] + csq4[KC + t] + csq4[2 * KC + t] + csq4[3 * KC + t];
    cnt_l[t] = 0;
  }

  f32x4 acc = (f32x4){0.f, 0.f, 0.f, 0.f};

  for (int kt = 0; kt < DMODEL; kt += 128) {
    __syncthreads();
    #pragma unroll
    for (int h = 0; h < 2; ++h) {
      if (w < 2) {                           // E rows 0..15 (waves 0-1)
        const int r = w * 8 + lrow;
        const size_t ga = (size_t)(p0 + r) * DMODEL + kt + h * 64 + csrc * 8;
        load_lds16(Eh + ga, &sEh[h][r * 64 + sl8 * 8]);
        load_lds16(El + ga, &sEl[h][r * 64 + sl8 * 8]);
      }
      #pragma unroll
      for (int i = 0; i < 2; ++i) {          // C rows 0..63 (16/wave)
        const int r = w * 16 + i * 8 + lrow;
        const size_t gc = (size_t)r * DMODEL + kt + h * 64 + csrc * 8;
        load_lds16(Ch + gc, &sCh[h][r * 64 + sl8 * 8]);
        load_lds16(Cl + gc, &sCl[h][r * 64 + sl8 * 8]);
      }
    }
    __syncthreads();
    #pragma unroll
    for (int kk4 = 0; kk4 < 4; ++kk4) {      // K: 0-31,32-63,64-95,96-127
      const int h = kk4 >> 1, kk2 = kk4 & 1;
      const int sl = ((kk2 * 4 + (lane >> 4)) ^ (lane & 7)) * 8;
      bf16x8 eh, el, ch, cl;
      {
        int off = (lane & 15) * 64 + sl;     // E rows 0..15
        eh = *(const bf16x8*)&sEh[h][off];
        el = *(const bf16x8*)&sEl[h][off];
      }
      {
        int off = (w * 16 + (lane & 15)) * 64 + sl;   // C quadrant w
        ch = *(const bf16x8*)&sCh[h][off];
        cl = *(const bf16x8*)&sCl[h][off];
      }
      acc = __builtin_amdgcn_mfma_f32_16x16x32_bf16(eh, ch, acc, 0, 0, 0);
      acc = __builtin_amdgcn_mfma_f32_16x16x32_bf16(eh, cl, acc, 0, 0, 0);
      acc = __builtin_amdgcn_mfma_f32_16x16x32_bf16(el, ch, acc, 0, 0, 0);
    }
  }
  {
    const int p = (lane >> 4) * 4;
    const int k = w * 16 + (lane & 15);
    const float csq = csq_l[k];
    #pragma unroll
    for (int r = 0; r < 4; ++r)
      Dmat[p + r][k] = csq - 2.f * acc[r];
  }
  __syncthreads();
  if (t < 16) {
    float best = Dmat[t][0]; int bi = 0;
    #pragma unroll 8
    for (int k = 1; k < KC; ++k) {
      float v = Dmat[t][k];
      if (v < best) { best = v; bi = k; }
    }
    ids[p0 + t] = bi;
    atomicAdd(&cnt_l[bi], 1);
  }
  __syncthreads();
  if (t < 64) pcnt[(size_t)blockIdx.x * KC + t] = (float)cnt_l[t];
}

// ---------------------------------------------------------------------------
// k2 segsum: single 128-point pass (both 64-halves staged at once).
// grid (4 dq, 64 g), block 256 (4 waves).  [R8 verbatim]
// ---------------------------------------------------------------------------
__global__ __launch_bounds__(256) void k2_segsum(
    const unsigned short* __restrict__ Eth, const unsigned short* __restrict__ Etl,
    const int* __restrict__ ids, const int* __restrict__ done,
    float* __restrict__ psum) {
  if (*done) return;
  __shared__ unsigned short sOH[64 * 136] __attribute__((aligned(16)));
  __shared__ unsigned short sTh[2][128 * 64] __attribute__((aligned(16)));
  __shared__ unsigned short sTl[2][128 * 64] __attribute__((aligned(16)));
  __shared__ int ids_l[128];
  const int t = threadIdx.x;
  const int w = t >> 6, lane = t & 63;
  const int dq = blockIdx.x, g = blockIdx.y;
  const int lrow = lane >> 3, sl8 = lane & 7;
  const int csrc = sl8 ^ lrow;

  if (t < 128) ids_l[t] = ids[g * 128 + t];
  __syncthreads();
  #pragma unroll
  for (int h = 0; h < 2; ++h) {
    #pragma unroll
    for (int i = 0; i < 4; ++i) {
      const int rr = w * 32 + i * 8 + lrow;   // d-row 0..127
      const size_t gt = (size_t)(dq * 128 + rr) * NPT + g * 128 + h * 64 + csrc * 8;
      load_lds16(Eth + gt, &sTh[h][rr * 64 + sl8 * 8]);
      load_lds16(Etl + gt, &sTl[h][rr * 64 + sl8 * 8]);
    }
  }
  #pragma unroll
  for (int q = 0; q < 4; ++q) {
    int c = t * 4 + q;                  // 1024 chunks: 64 cl x 16 p-chunks
    int cl = c >> 4, pc = c & 15;
    unsigned short v[8];
    #pragma unroll
    for (int j = 0; j < 8; ++j)
      v[j] = (ids_l[pc * 8 + j] == cl) ? (unsigned short)0x3F80 : (unsigned short)0;
    *(uint4*)&sOH[cl * 136 + pc * 8] = *(uint4*)&v[0];
  }

  f32x4 acc[4][2];
  #pragma unroll
  for (int i = 0; i < 4; ++i)
    #pragma unroll
    for (int j = 0; j < 2; ++j) acc[i][j] = (f32x4){0.f, 0.f, 0.f, 0.f};

  __syncthreads();
  #pragma unroll
  for (int kk4 = 0; kk4 < 4; ++kk4) {   // points 0-31,32-63,64-95,96-127
    const int h = kk4 >> 1, kk2 = kk4 & 1;
    const int quad = lane >> 4;
    const int poff = kk4 * 32 + quad * 8;
    bf16x8 a[4], bh[2], bl[2];
    #pragma unroll
    for (int mi = 0; mi < 4; ++mi)
      a[mi] = *(const bf16x8*)&sOH[(mi * 16 + (lane & 15)) * 136 + poff];
    const int sl = ((kk2 * 4 + quad) ^ (lane & 7)) * 8;
    #pragma unroll
    for (int ni = 0; ni < 2; ++ni) {
      int off = (w * 32 + ni * 16 + (lane & 15)) * 64 + sl;
      bh[ni] = *(const bf16x8*)&sTh[h][off];
      bl[ni] = *(const bf16x8*)&sTl[h][off];
    }
    #pragma unroll
    for (int mi = 0; mi < 4; ++mi)
      #pragma unroll
      for (int ni = 0; ni < 2; ++ni) {
        acc[mi][ni] = __builtin_amdgcn_mfma_f32_16x16x32_bf16(a[mi], bh[ni], acc[mi][ni], 0, 0, 0);
        acc[mi][ni] = __builtin_amdgcn_mfma_f32_16x16x32_bf16(a[mi], bl[ni], acc[mi][ni], 0, 0, 0);
      }
  }
  #pragma unroll
  for (int mi = 0; mi < 4; ++mi)
    #pragma unroll
    for (int ni = 0; ni < 2; ++ni) {
      const int cl = mi * 16 + (lane >> 4) * 4;
      const int d = dq * 128 + w * 32 + ni * 16 + (lane & 15);
      #pragma unroll
      for (int r = 0; r < 4; ++r)
        psum[((size_t)g * KC + cl + r) * DMODEL + d] = acc[mi][ni][r];
    }
}

// ---------------------------------------------------------------------------
// k3 update: reduce psum (fixed g order, unroll-16), new cent (+hi/lo),
// shift, done, csq4; on is_last also one-hot + cent copy.
// pcnt has 512 groups (counts = integers, exact in any sum order).
// grid 256, block 128.
// ---------------------------------------------------------------------------
__global__ __launch_bounds__(128) void k3_update(float* __restrict__ cent,
    unsigned short* __restrict__ centh, unsigned short* __restrict__ centl,
    const float* __restrict__ psum, const float* __restrict__ pcnt,
    int* __restrict__ done, float* __restrict__ csq4,
    float* __restrict__ shift2, int* __restrict__ ticket, int iter,
    const int* __restrict__ ids, float* __restrict__ out, int is_last) {
  const int dn = *done;
  const int bk = blockIdx.x & 63, dq = blockIdx.x >> 6;
  const int t = threadIdx.x;
  const int d = dq * 128 + t;
  __shared__ float red[128];
  __shared__ float cnt_s;
  float outv = 0.f;
  if (!dn) {
    red[t] = pcnt[(size_t)(4 * t) * KC + bk] + pcnt[(size_t)(4 * t + 1) * KC + bk]
           + pcnt[(size_t)(4 * t + 2) * KC + bk] + pcnt[(size_t)(4 * t + 3) * KC + bk];
    __syncthreads();
    for (int s = 64; s > 0; s >>= 1) { if (t < s) red[t] += red[t + s]; __syncthreads(); }
    if (t == 0) cnt_s = red[0];
    __syncthreads();
    const float count = cnt_s;
    float s = 0.f;
    #pragma unroll 16
    for (int g = 0; g < 64; ++g)
      s += psum[((size_t)g * KC + bk) * DMODEL + d];
    float oldv = cent[bk * DMODEL + d];
    float newv = (count > 0.f) ? (s / fmaxf(count, 1.f)) : oldv;
    cent[bk * DMODEL + d] = newv;
    unsigned short h = bf16_rn(newv);
    centh[bk * DMODEL + d] = h;
    centl[bk * DMODEL + d] = bf16_rn(newv - __uint_as_float((unsigned)h << 16));
    outv = newv;
    float df = newv - oldv;
    red[t] = df * df; __syncthreads();
    for (int s2 = 64; s2 > 0; s2 >>= 1) { if (t < s2) red[t] += red[t + s2]; __syncthreads(); }
    float tot_sh = red[0]; __syncthreads();
    red[t] = newv * newv; __syncthreads();
    for (int s2 = 64; s2 > 0; s2 >>= 1) { if (t < s2) red[t] += red[t + s2]; __syncthreads(); }
    if (t == 0) {
      csq4[dq * KC + bk] = red[0];
      atomicAdd(shift2 + iter, tot_sh);
      __threadfence();
      int tk = atomicAdd(ticket + iter, 1);
      if (tk == 255) {
        float tot = atomicAdd(shift2 + iter, 0.f);
        if (sqrtf(tot) < 1e-4f) *done = 1;
      }
    }
  } else {
    outv = cent[bk * DMODEL + d];
  }
  if (is_last) {
    out[(size_t)NPT * KC + bk * DMODEL + d] = outv;
    const int n = blockIdx.x * 32 + (t >> 2);
    const int k0 = (t & 3) * 16;
    const int idn = ids[n];
    #pragma unroll
    for (int j = 0; j < 4; ++j) {
      float4 v;
      v.x = (idn == k0 + j * 4 + 0) ? 1.f : 0.f;
      v.y = (idn == k0 + j * 4 + 1) ? 1.f : 0.f;
      v.z = (idn == k0 + j * 4 + 2) ? 1.f : 0.f;
      v.w = (idn == k0 + j * 4 + 3) ? 1.f : 0.f;
      *(float4*)(out + (size_t)n * KC + k0 + j * 4) = v;
    }
  }
}

// ---------------------------------------------------------------------------
extern "C" void kernel_launch(void* const* d_in, const int* in_sizes, int n_in,
                              void* d_out, int out_size, void* d_ws, size_t ws_size,
                              hipStream_t stream) {
  const float* x    = (const float*)d_in[0];
  const float* W    = (const float*)d_in[1];
  const float* bias = (const float*)d_in[2];
  const float* c0   = (const float*)d_in[3];
  float* out = (float*)d_out;
  float* emb_out = out + NPT * KC + KC * DMODEL;

  char* ws = (char*)d_ws;
  unsigned short* Ehi  = (unsigned short*)(ws + 0);
  unsigned short* Elo  = (unsigned short*)(ws + 8388608);
  unsigned short* Eth  = (unsigned short*)(ws + 16777216);
  unsigned short* Etl  = (unsigned short*)(ws + 25165824);
  float* psum    = (float*)(ws + 33554432);
  float* cent    = (float*)(ws + 41943040);
  unsigned short* centh = (unsigned short*)(ws + 42074112);
  unsigned short* centl = (unsigned short*)(ws + 42139648);
  float* csq4    = (float*)(ws + 42205184);
  float* shift2  = (float*)(ws + 42206208);
  int*   ticket  = (int*)(ws + 42206272);
  int*   done_f  = (int*)(ws + 42206336);
  float* pcnt    = (float*)(ws + 42206400);   // 512*64 floats = 128KB
  int*   ids     = (int*)(ws + 42337472);     // 8192 ints = 32KB -> ends 42370240
  unsigned short* Xh = (unsigned short*)(ws + 0);
  unsigned short* Xl = (unsigned short*)(ws + 33554432);
  unsigned short* Wh = (unsigned short*)(ws + 67108864);
  unsigned short* Wl = (unsigned short*)(ws + 69206016);
  const size_t need_fast = 71303168;
  (void)n_in; (void)in_sizes; (void)out_size;

  if (ws_size >= need_fast) {
    prep_k<<<4096, 256, 0, stream>>>(x, Xh, Xl, W, Wh, Wl);
    gemm_mfma<<<dim3(128, 4), 256, 0, stream>>>(Xh, Xl, Wh, Wl, bias, emb_out);
  } else {
    gemm_emb<<<dim3(4, BSZ), 256, 0, stream>>>(x, W, bias, emb_out);
  }
  conv_et<<<dim3(8, 128), 256, 0, stream>>>(emb_out, Ehi, Elo, Eth, Etl,
                                            c0, cent, centh, centl, csq4,
                                            done_f, shift2, ticket);
  for (int it = 0; it < MAXIT; ++it) {
    k1_assign<<<512, 256, 0, stream>>>(Ehi, Elo, centh, centl, csq4, done_f, ids, pcnt);
    k2_segsum<<<dim3(4, 64), 256, 0, stream>>>(Eth, Etl, ids, done_f, psum);
    k3_update<<<256, 128, 0, stream>>>(cent, centh, centl, psum, pcnt, done_f,
                                       csq4, shift2, ticket, it,
                                       ids, out, it == MAXIT - 1);
  }
}